// Round 14
// baseline (899.371 us; speedup 1.0000x reference)
//
#include <hip/hip_runtime.h>

// VQ-VAE EMA vector quantizer, MI355X.
// R14: occupancy theory test. R6-R13 invariant explained: acc(128 AGPR) +
// arch(128 VGPR) = 256 regs/thread -> 2 waves/SIMD -> one 8-wave barrier
// domain/CU -> staging stuck at ~9.3 B/cyc. New argmin_hi: 256-thr blocks,
// BC=128 (acc=64 regs, total ~165, launch_bounds(256,3)) -> 3 co-resident
// 4-wave blocks = 3 independent barrier domains (m114/m97 mechanism).
// Also: cb prep fused into one kernel. Rest = R13.

constexpr int N = 32768;   // B*L
constexpr int D = 512;
constexpr int K = 8192;
constexpr int CAP  = 8192;
constexpr int CAPE = 4096;

constexpr float DECAYF  = 0.99f;
constexpr float OMDECAY = (float)(1.0 - 0.99);
constexpr float EPSF    = 1e-6f;
constexpr float KEPSF   = (float)(8192 * 1e-6);
constexpr float TAU1    = 1.0f;
constexpr float TAU2    = 0.02f;

typedef unsigned int       u32;
typedef unsigned short     u16;
typedef unsigned long long u64;
typedef float  f32x4 __attribute__((ext_vector_type(4)));
typedef u32    u32x4 __attribute__((ext_vector_type(4)));
typedef __bf16 bf16x8 __attribute__((ext_vector_type(8)));

#define AS1 __attribute__((address_space(1)))
#define AS3 __attribute__((address_space(3)))

// ---- workspace layout (32-bit word offsets) ----
constexpr size_t OFF_CNORM  = 0;                          // K f32
constexpr size_t OFF_IDX    = OFF_CNORM + K;              // N int
constexpr size_t OFF_CNTI   = OFF_IDX + N;                // K int
constexpr size_t OFF_FLAGC  = OFF_CNTI + K;               // 1 int
constexpr size_t OFF_FLAG2C = OFF_FLAGC + 1;              // 1 int
constexpr size_t OFF_NEXT   = OFF_FLAG2C + 1;             // K int
constexpr size_t OFF_OFFS   = OFF_NEXT + K;               // K+1 int
constexpr size_t OFF_LIST   = OFF_OFFS + K + 1;           // N int
constexpr size_t OFF_FLAGL  = OFF_LIST + N;               // CAP int
constexpr size_t OFF_FLAG2L = OFF_FLAGL + CAP;            // N int
constexpr size_t OFF_PB1    = OFF_FLAG2L + N;             // 16*CAP f32
constexpr size_t OFF_PB2    = OFF_PB1 + 16 * CAP;         // 16*CAP f32
constexpr size_t OFF_PI1    = OFF_PB2 + 16 * CAP;         // 16*CAP int
constexpr size_t OFF_ESLOT  = (OFF_PI1 + 16 * CAP + 1) & ~(size_t)1;
constexpr size_t OFF_SUMS   = (OFF_ESLOT + 2 * CAPE + 1) & ~(size_t)1;
constexpr size_t OFF_LOSSP  = (OFF_SUMS + 2 + 1) & ~(size_t)1;
constexpr size_t OFF_CBH    = (OFF_LOSSP + 2 * K + 3) & ~(size_t)3;
static_assert((OFF_ESLOT & 1) == 0 && (OFF_SUMS & 1) == 0 && (OFF_LOSSP & 1) == 0, "align");
static_assert((OFF_CBH & 3) == 0, "16B align for global_load_lds");

// ---- output layout (float offsets) ----
constexpr size_t OUT_ZQ   = 0;
constexpr size_t OUT_IDX  = OUT_ZQ + (size_t)N * D;
constexpr size_t OUT_LOSS = OUT_IDX + N;
constexpr size_t OUT_NCB  = OUT_LOSS + 1;
constexpr size_t OUT_NCS  = OUT_NCB + (size_t)K * D;
constexpr size_t OUT_EMA  = OUT_NCS + K;
constexpr size_t XH_F  = OUT_ZQ;
constexpr size_t PX2_F = OUT_ZQ + (size_t)N * 256;
constexpr size_t PB1H_F = OUT_EMA;
constexpr size_t PB2H_F = OUT_EMA + 4 * (size_t)N;
constexpr size_t PI1H_F = OUT_EMA + 8 * (size_t)N;

// ---------------------------------------------------------------------------
__device__ inline u16 f32_to_bf16_rne(float f)
{
    u32 u = __builtin_bit_cast(u32, f);
    u = (u + 0x7FFFu + ((u >> 16) & 1u)) >> 16;
    return (u16)u;
}

// hi-only split of z_e: [rows/16][16 slices][64 lanes][8 u16]
__global__ __launch_bounds__(256) void split_hi_kernel(const float* __restrict__ src,
                                                       u32x4* __restrict__ dst)
{
    const int T = blockIdx.x;
    const int w = threadIdx.x >> 6;
    const int l = threadIdx.x & 63;
    const int row = T * 16 + (l & 15);
#pragma unroll
    for (int i = 0; i < 4; ++i) {
        const int S  = w * 4 + i;
        const int q4 = S * 8 + (l >> 4) * 2;
        const float4 va = ((const float4*)src)[(size_t)row * 128 + q4];
        const float4 vb = ((const float4*)src)[(size_t)row * 128 + q4 + 1];
        const float a[8] = {va.x, va.y, va.z, va.w, vb.x, vb.y, vb.z, vb.w};
        u32x4 o;
#pragma unroll
        for (int j = 0; j < 4; ++j)
            ((u32*)&o)[j] = (u32)f32_to_bf16_rne(a[2 * j]) |
                            ((u32)f32_to_bf16_rne(a[2 * j + 1]) << 16);
        dst[((size_t)T * 16 + S) * 64 + l] = o;
    }
}

// fused codebook prep: hi-split -> CBH, interleaved split -> CB2, norms -> cnorm
__global__ __launch_bounds__(256) void cbprep_kernel(const float* __restrict__ cb,
                                                     u32x4* __restrict__ CBH,
                                                     u32x4* __restrict__ CB2,
                                                     float* __restrict__ cnorm)
{
    const int T = blockIdx.x;
    const int w = threadIdx.x >> 6;
    const int l = threadIdx.x & 63;
    // phase A: hi-split
    {
        const int row = T * 16 + (l & 15);
#pragma unroll
        for (int i = 0; i < 4; ++i) {
            const int S  = w * 4 + i;
            const int q4 = S * 8 + (l >> 4) * 2;
            const float4 va = ((const float4*)cb)[(size_t)row * 128 + q4];
            const float4 vb = ((const float4*)cb)[(size_t)row * 128 + q4 + 1];
            const float a[8] = {va.x, va.y, va.z, va.w, vb.x, vb.y, vb.z, vb.w};
            u32x4 o;
#pragma unroll
            for (int j = 0; j < 4; ++j)
                ((u32*)&o)[j] = (u32)f32_to_bf16_rne(a[2 * j]) |
                                ((u32)f32_to_bf16_rne(a[2 * j + 1]) << 16);
            CBH[((size_t)T * 16 + S) * 64 + l] = o;
        }
    }
    // phase B: interleaved (hi,lo) split
    {
        const int row = T * 16 + (l & 15);
        const int cq  = l >> 4;
#pragma unroll
        for (int i = 0; i < 8; ++i) {
            const int S = w + 4 * i;
            const float4 v = ((const float4*)cb)[(size_t)row * 128 + S * 4 + cq];
            u32x4 o;
            const float a[4] = {v.x, v.y, v.z, v.w};
#pragma unroll
            for (int j = 0; j < 4; ++j) {
                const u16 hi = f32_to_bf16_rne(a[j]);
                const float hif = __builtin_bit_cast(float, (u32)hi << 16);
                const u16 lo = f32_to_bf16_rne(a[j] - hif);
                ((u32*)&o)[j] = (u32)hi | ((u32)lo << 16);
            }
            CB2[((size_t)T * 32 + S) * 64 + l] = o;
        }
    }
    // phase C: row norms (4 rows per pass, 4 passes)
#pragma unroll
    for (int sub = 0; sub < 4; ++sub) {
        const int row = T * 16 + sub * 4 + w;
        const float4* r = (const float4*)(cb + (size_t)row * D);
        const float4 v0 = r[l];
        const float4 v1 = r[l + 64];
        float s = v0.x * v0.x + v0.y * v0.y + v0.z * v0.z + v0.w * v0.w
                + v1.x * v1.x + v1.y * v1.y + v1.z * v1.z + v1.w * v1.w;
#pragma unroll
        for (int m = 32; m >= 1; m >>= 1) s += __shfl_xor(s, m, 64);
        if (l == 0) cnorm[row] = s;
    }
}

// indirect split of flagged points -> PX2 interleaved frag order
__global__ __launch_bounds__(256) void repack_kernel(
    const float* __restrict__ z_e, const int* __restrict__ flag_cnt,
    const int* __restrict__ flag_list, u32x4* __restrict__ PX2)
{
    const int B = blockIdx.x;
    const int cnt = min(*flag_cnt, CAP);
    if (B * 16 >= cnt) return;
    const int w = threadIdx.x >> 6;
    const int l = threadIdx.x & 63;
    const int srow = B * 16 + (l & 15);
    const int n = (srow < cnt) ? (flag_list[srow] & (N - 1)) : 0;
    const int cq = l >> 4;
#pragma unroll
    for (int i = 0; i < 8; ++i) {
        const int S = w + 4 * i;
        const float4 v = ((const float4*)z_e)[(size_t)n * 128 + S * 4 + cq];
        u32x4 o;
        const float a[4] = {v.x, v.y, v.z, v.w};
#pragma unroll
        for (int j = 0; j < 4; ++j) {
            const u16 hi = f32_to_bf16_rne(a[j]);
            const float hif = __builtin_bit_cast(float, (u32)hi << 16);
            const u16 lo = f32_to_bf16_rne(a[j] - hif);
            ((u32*)&o)[j] = (u32)hi | ((u32)lo << 16);
        }
        PX2[((size_t)B * 32 + S) * 64 + l] = o;
    }
}

// ---------------------------------------------------------------------------
// Pass 1: hi-only argmin. 256 thr (4 waves), BP=128 pts, BC=128 codes/chunk,
// K-quarter split (16 chunks/quarter), 2x16KB LDS. acc=16 f32x4 (64 regs) ->
// total ~165 regs -> 3 waves/SIMD -> 3 co-resident blocks (3 barrier domains).
constexpr int BPH = 128, BCH = 128, KIH = 32;
constexpr int NSTEPH = 16;                 // slices per chunk
constexpr int NCHQ   = 16;                 // chunks per quarter (2048/128)
constexpr int TOTQ   = NCHQ * NSTEPH;      // 256 steps/block
constexpr int CELH = BCH * KIH;            // 4096 u16 (8KB)
constexpr int XELH = BPH * KIH;            // 4096 u16 (8KB)
constexpr int BUFH = CELH + XELH;          // 8192 u16 (16KB)

__global__ __launch_bounds__(256, 3) void argmin_hi_kernel(
    const u16* __restrict__ CBH, const u16* __restrict__ XH,
    const float* __restrict__ cnorm,
    float* __restrict__ pb1h, float* __restrict__ pb2h, int* __restrict__ pi1h)
{
    __shared__ __align__(16) u16 lds[2][BUFH];   // 32 KB -> 3+ blocks/CU

    const int b    = blockIdx.x;
    const int kq   = (b & 7) >> 1;               // K quarter (XCD-affine)
    const int n0   = ((b >> 3) * 2 + (b & 1)) * BPH;
    const int tid  = threadIdx.x;
    const int w    = tid >> 6;                   // 0..3
    const int lane = tid & 63;
    const int lhi  = lane >> 4;

    // incremental u16 offsets. CBH layout [K/16][16][64][8]: group stride 8192,
    // slice stride 512. Quarter base = kq*128 groups = kq*1048576 u16.
    u32 cbo[2], xo[2];
#pragma unroll
    for (int m = 0; m < 2; ++m) {
        const int flat = m * 256 + tid;          // [0,512)
        cbo[m] = (u32)(kq * 1048576 + (flat >> 6) * 8192 + (flat & 63) * 8);
        xo[m]  = (u32)((n0 / 16 + (flat >> 6)) * 8192 + (flat & 63) * 8);
    }

    auto stage = [&](int parity) {
        u16* bufp = &lds[parity][0];
#pragma unroll
        for (int m = 0; m < 2; ++m) {
            __builtin_amdgcn_global_load_lds((const AS1 u32*)(CBH + cbo[m]),
                (AS3 u32*)(bufp + (m * 256 + tid) * 8), 16, 0, 0);
            cbo[m] += 512;
            __builtin_amdgcn_global_load_lds((const AS1 u32*)(XH + xo[m]),
                (AS3 u32*)(bufp + CELH + (m * 256 + tid) * 8), 16, 0, 0);
            xo[m] += 512;
        }
    };

    float b1[8], b2[8]; int i1[8];
#pragma unroll
    for (int p = 0; p < 8; ++p) { b1[p] = INFINITY; b2[p] = INFINITY; i1[p] = 0; }

    stage(0);
    __syncthreads();
    int sc = 1;

    for (int cc = 0; cc < NCHQ; ++cc) {
        f32x4 acc[2][8];
        const f32x4 zero = {0.f, 0.f, 0.f, 0.f};
#pragma unroll
        for (int cg = 0; cg < 2; ++cg)
#pragma unroll
            for (int p = 0; p < 8; ++p) acc[cg][p] = zero;

        for (int s8 = 0; s8 < NSTEPH; ++s8) {
            const u16* cur = &lds[s8 & 1][0];
            if (sc < TOTQ) {
                if ((sc & (NSTEPH - 1)) == 0) {  // crossing into next chunk
#pragma unroll
                    for (int m = 0; m < 2; ++m) { cbo[m] += 65536 - 8192; xo[m] -= 8192; }
                }
                stage(sc & 1);
                ++sc;
            }
            u32x4 bfr[8];
#pragma unroll
            for (int p = 0; p < 8; ++p)
                bfr[p] = *(const u32x4*)(cur + CELH + p * 512 + lane * 8);
#pragma unroll
            for (int cg = 0; cg < 2; ++cg) {
                const u32x4 af = *(const u32x4*)(cur + (w * 2 + cg) * 512 + lane * 8);
#pragma unroll
                for (int p = 0; p < 8; ++p)
                    acc[cg][p] = __builtin_amdgcn_mfma_f32_16x16x32_bf16(
                        __builtin_bit_cast(bf16x8, af),
                        __builtin_bit_cast(bf16x8, bfr[p]), acc[cg][p], 0, 0, 0);
            }
            __syncthreads();
        }

        const int cb0 = (kq * NCHQ + cc) * BCH + w * 32;
#pragma unroll
        for (int cg = 0; cg < 2; ++cg) {
            const int code0 = cb0 + cg * 16 + lhi * 4;
            const float4 cn4 = *(const float4*)(cnorm + code0);
            const float cn[4] = {cn4.x, cn4.y, cn4.z, cn4.w};
#pragma unroll
            for (int p = 0; p < 8; ++p) {
                const f32x4 A = acc[cg][p];
                const float dv[4] = {cn[0] - 2.f * A.x, cn[1] - 2.f * A.y,
                                     cn[2] - 2.f * A.z, cn[3] - 2.f * A.w};
#pragma unroll
                for (int r = 0; r < 4; ++r) {
                    if (dv[r] < b1[p]) { b2[p] = b1[p]; b1[p] = dv[r]; i1[p] = code0 + r; }
                    else if (dv[r] < b2[p]) { b2[p] = dv[r]; }
                }
            }
        }
    }

#pragma unroll
    for (int p = 0; p < 8; ++p) {
#pragma unroll
        for (int m = 16; m <= 32; m <<= 1) {
            const float ob1 = __shfl_xor(b1[p], m, 64);
            const float ob2 = __shfl_xor(b2[p], m, 64);
            const int   oi1 = __shfl_xor(i1[p], m, 64);
            const float nb2 = fminf(fminf(b2[p], ob2), fmaxf(b1[p], ob1));
            if (ob1 < b1[p] || (ob1 == b1[p] && oi1 < i1[p])) { b1[p] = ob1; i1[p] = oi1; }
            b2[p] = nb2;
        }
    }

    __syncthreads();

    float* mb1 = (float*)&lds[0][0];
    float* mb2 = mb1 + 4 * BPH;
    int*   mi  = (int*)(mb2 + 4 * BPH);
    if (lane < 16) {
#pragma unroll
        for (int p = 0; p < 8; ++p) {
            const int pt = p * 16 + lane;
            mb1[w * BPH + pt] = b1[p];
            mb2[w * BPH + pt] = b2[p];
            mi [w * BPH + pt] = i1[p];
        }
    }
    __syncthreads();
    if (tid < BPH) {
        float fb1 = INFINITY, fb2 = INFINITY; int fi = 0;
        for (int ww = 0; ww < 4; ++ww) {
            const float a1 = mb1[ww * BPH + tid], a2 = mb2[ww * BPH + tid];
            const int   ai = mi[ww * BPH + tid];
            const float nb2 = fminf(fminf(fb2, a2), fmaxf(fb1, a1));
            if (a1 < fb1 || (a1 == fb1 && ai < fi)) { fb1 = a1; fi = ai; }
            fb2 = nb2;
        }
        const int n = n0 + tid;
        pb1h[kq * N + n] = fb1;
        pb2h[kq * N + n] = fb2;
        pi1h[kq * N + n] = fi;
    }
}

// ---------------------------------------------------------------------------
__global__ __launch_bounds__(256) void merge_hi_kernel(
    const float* __restrict__ pb1h, const float* __restrict__ pb2h,
    const int* __restrict__ pi1h,
    int* __restrict__ idx_i, float* __restrict__ idx_f,
    int* __restrict__ flag_cnt, int* __restrict__ flag_list,
    int* __restrict__ flag2_cnt, int* __restrict__ flag2_list)
{
    const int n = blockIdx.x * 256 + threadIdx.x;
    float fb1 = INFINITY, fb2 = INFINITY; int fi = 0x7fffffff;
#pragma unroll
    for (int q = 0; q < 4; ++q) {
        const float a1 = pb1h[q * N + n], a2 = pb2h[q * N + n];
        const int   ai = pi1h[q * N + n];
        const float nb2 = fminf(fminf(fb2, a2), fmaxf(fb1, a1));
        if (a1 < fb1 || (a1 == fb1 && ai < fi)) { fb1 = a1; fi = ai; }
        fb2 = nb2;
    }
    idx_i[n] = fi;
    idx_f[n] = (float)fi;
    if (fb2 - fb1 < TAU1) {
        const int pos = atomicAdd(flag_cnt, 1);
        if (pos < CAP) flag_list[pos] = n;
        else {
            const int p2 = atomicAdd(flag2_cnt, 1);
            if ((unsigned)p2 < (unsigned)N) flag2_list[p2] = n;
        }
    }
}

// ---------------------------------------------------------------------------
// Pass 2: split-precision argmin, ONE 512-code chunk per block.
constexpr int CEL2 = 512 * 32;
constexpr int XEL2 = 128 * 32;
constexpr int BUF2 = CEL2 + XEL2;

__global__ __launch_bounds__(512, 2) void argmin_part_kernel(
    const u16* __restrict__ CB2, const u16* __restrict__ PX2,
    const float* __restrict__ cnorm, const int* __restrict__ flag_cnt,
    float* __restrict__ pb1, float* __restrict__ pb2, int* __restrict__ pi1)
{
    const int q  = blockIdx.x & 15;
    const int sb = blockIdx.x >> 4;
    const int cnt = min(*flag_cnt, CAP);
    if (sb * 128 >= cnt) return;
    const int n0s = sb * 128;

    __shared__ __align__(16) u16 lds[2][BUF2];

    const int tid  = threadIdx.x;
    const int w    = tid >> 6;
    const int lane = tid & 63;
    const int lhi  = lane >> 4;

    auto stage = [&](u16* bufp, int s) {
#pragma unroll
        for (int j = 0; j < 4; ++j) {
            const int slot = j * 512 + tid;
            const u16* gsrc = CB2 + (((size_t)(q * 32 + (slot >> 6)) * 32 + s) * 512
                                     + (slot & 63) * 8);
            __builtin_amdgcn_global_load_lds((const AS1 u32*)gsrc,
                                             (AS3 u32*)(bufp + slot * 8), 16, 0, 0);
        }
        const u16* gx = PX2 + (((size_t)(n0s / 16 + (tid >> 6)) * 32 + s) * 512
                               + (tid & 63) * 8);
        __builtin_amdgcn_global_load_lds((const AS1 u32*)gx,
                                         (AS3 u32*)(bufp + CEL2 + tid * 8), 16, 0, 0);
    };

    float b1[8], b2[8]; int i1[8];
#pragma unroll
    for (int p = 0; p < 8; ++p) { b1[p] = INFINITY; b2[p] = INFINITY; i1[p] = 0; }

    f32x4 acc[4][8];
    const f32x4 zero = {0.f, 0.f, 0.f, 0.f};
#pragma unroll
    for (int cg = 0; cg < 4; ++cg)
#pragma unroll
        for (int p = 0; p < 8; ++p) acc[cg][p] = zero;

    stage(&lds[0][0], 0);
    __syncthreads();

#pragma unroll 2
    for (int s = 0; s < 32; ++s) {
        const u16* cur = (s & 1) ? &lds[1][0] : &lds[0][0];
        u16* nxt       = (s & 1) ? &lds[0][0] : &lds[1][0];
        if (s + 1 < 32) stage(nxt, s + 1);

        u32x4 bfr[8];
#pragma unroll
        for (int p = 0; p < 8; ++p)
            bfr[p] = *(const u32x4*)(cur + CEL2 + p * 512 + lane * 8);
#pragma unroll
        for (int cg = 0; cg < 4; ++cg) {
            const u32x4 af = *(const u32x4*)(cur + (w * 4 + cg) * 512 + lane * 8);
            u32x4 as;
            as.x = (af.x >> 16) | (af.x << 16);
            as.y = (af.y >> 16) | (af.y << 16);
            as.z = (af.z >> 16) | (af.z << 16);
            as.w = (af.w >> 16) | (af.w << 16);
#pragma unroll
            for (int p = 0; p < 8; ++p) {
                acc[cg][p] = __builtin_amdgcn_mfma_f32_16x16x32_bf16(
                    __builtin_bit_cast(bf16x8, af), __builtin_bit_cast(bf16x8, bfr[p]),
                    acc[cg][p], 0, 0, 0);
                acc[cg][p] = __builtin_amdgcn_mfma_f32_16x16x32_bf16(
                    __builtin_bit_cast(bf16x8, as), __builtin_bit_cast(bf16x8, bfr[p]),
                    acc[cg][p], 0, 0, 0);
            }
        }
        __syncthreads();
    }

    const int cb0 = q * 512 + w * 64;
#pragma unroll
    for (int cg = 0; cg < 4; ++cg) {
        const int code0 = cb0 + cg * 16 + lhi * 4;
        const float4 cn4 = *(const float4*)(cnorm + code0);
        const float cn[4] = {cn4.x, cn4.y, cn4.z, cn4.w};
#pragma unroll
        for (int p = 0; p < 8; ++p) {
            const f32x4 A = acc[cg][p];
            const float dv[4] = {cn[0] - 2.f * A.x, cn[1] - 2.f * A.y,
                                 cn[2] - 2.f * A.z, cn[3] - 2.f * A.w};
#pragma unroll
            for (int r = 0; r < 4; ++r) {
                if (dv[r] < b1[p]) { b2[p] = b1[p]; b1[p] = dv[r]; i1[p] = code0 + r; }
                else if (dv[r] < b2[p]) { b2[p] = dv[r]; }
            }
        }
    }

#pragma unroll
    for (int p = 0; p < 8; ++p) {
#pragma unroll
        for (int m = 16; m <= 32; m <<= 1) {
            const float ob1 = __shfl_xor(b1[p], m, 64);
            const float ob2 = __shfl_xor(b2[p], m, 64);
            const int   oi1 = __shfl_xor(i1[p], m, 64);
            const float nb2 = fminf(fminf(b2[p], ob2), fmaxf(b1[p], ob1));
            if (ob1 < b1[p] || (ob1 == b1[p] && oi1 < i1[p])) { b1[p] = ob1; i1[p] = oi1; }
            b2[p] = nb2;
        }
    }

    __syncthreads();

    float* mb1 = (float*)&lds[0][0];
    float* mb2 = mb1 + 8 * 128;
    int*   mi  = (int*)(mb2 + 8 * 128);
    if (lane < 16) {
#pragma unroll
        for (int p = 0; p < 8; ++p) {
            const int pt = p * 16 + lane;
            mb1[w * 128 + pt] = b1[p];
            mb2[w * 128 + pt] = b2[p];
            mi [w * 128 + pt] = i1[p];
        }
    }
    __syncthreads();
    if (tid < 128) {
        float fb1 = INFINITY, fb2 = INFINITY; int fi = 0;
        for (int ww = 0; ww < 8; ++ww) {
            const float a1 = mb1[ww * 128 + tid], a2 = mb2[ww * 128 + tid];
            const int   ai = mi[ww * 128 + tid];
            const float nb2 = fminf(fminf(fb2, a2), fmaxf(fb1, a1));
            if (a1 < fb1 || (a1 == fb1 && ai < fi)) { fb1 = a1; fi = ai; }
            fb2 = nb2;
        }
        const int slot = n0s + tid;
        pb1[q * CAP + slot] = fb1;
        pb2[q * CAP + slot] = fb2;
        pi1[q * CAP + slot] = fi;
    }
}

// ---------------------------------------------------------------------------
__global__ __launch_bounds__(256) void combine_kernel(
    const int* __restrict__ flag_cnt, const int* __restrict__ flag_list,
    const float* __restrict__ pb1, const float* __restrict__ pb2,
    const int* __restrict__ pi1,
    int* __restrict__ idx_i, float* __restrict__ idx_f,
    int* __restrict__ flag2_cnt, int* __restrict__ flag2_list)
{
    const int s = blockIdx.x * 256 + threadIdx.x;
    const int cnt = min(*flag_cnt, CAP);
    if (s >= cnt) return;
    float fb1 = INFINITY, fb2 = INFINITY; int fi = 0x7fffffff;
#pragma unroll
    for (int q = 0; q < 16; ++q) {
        const float a1 = pb1[q * CAP + s], a2 = pb2[q * CAP + s];
        const int   ai = pi1[q * CAP + s];
        const float nb2 = fminf(fminf(fb2, a2), fmaxf(fb1, a1));
        if (a1 < fb1 || (a1 == fb1 && ai < fi)) { fb1 = a1; fi = ai; }
        fb2 = nb2;
    }
    const int n = flag_list[s] & (N - 1);
    idx_i[n] = fi;
    idx_f[n] = (float)fi;
    if (fb2 - fb1 < TAU2) {
        const int p2 = atomicAdd(flag2_cnt, 1);
        if ((unsigned)p2 < (unsigned)N) flag2_list[p2] = n;
    }
}

// ---------------------------------------------------------------------------
__global__ __launch_bounds__(256) void exact_part_kernel(
    const float* __restrict__ x, const float* __restrict__ cb,
    const float* __restrict__ cnorm, const int* __restrict__ flag2_cnt,
    const int* __restrict__ flag2_list, u64* __restrict__ eslot)
{
    __shared__ float4 xs[128];
    __shared__ u64 red[256];
    const int cnt = min(*flag2_cnt, CAPE);
    const int nwork = cnt * 16;
    for (int j = blockIdx.x; j < nwork; j += gridDim.x) {
        const int s = j >> 4;
        const int q = j & 15;
        const int n = flag2_list[s] & (N - 1);
        __syncthreads();
        if (threadIdx.x < 128)
            xs[threadIdx.x] = ((const float4*)(x + (size_t)n * D))[threadIdx.x];
        __syncthreads();
        u64 bestp = ~0ull;
#pragma unroll
        for (int c = 0; c < 2; ++c) {
            const int k = q * 512 + c * 256 + threadIdx.x;
            const float4* crow = (const float4*)(cb + (size_t)k * D);
            float a0 = 0.f, a1 = 0.f, a2 = 0.f, a3 = 0.f;
            for (int d = 0; d < 128; ++d) {
                const float4 xv = xs[d], cv = crow[d];
                a0 = fmaf(xv.x, cv.x, a0);
                a1 = fmaf(xv.y, cv.y, a1);
                a2 = fmaf(xv.z, cv.z, a2);
                a3 = fmaf(xv.w, cv.w, a3);
            }
            const float dist = cnorm[k] - 2.0f * ((a0 + a1) + (a2 + a3));
            u32 ub = __builtin_bit_cast(u32, dist);
            ub = (ub & 0x80000000u) ? ~ub : (ub | 0x80000000u);
            const u64 pk = ((u64)ub << 32) | (u32)k;
            bestp = bestp < pk ? bestp : pk;
        }
        red[threadIdx.x] = bestp;
        __syncthreads();
        for (int off = 128; off > 0; off >>= 1) {
            if (threadIdx.x < off) {
                const u64 o = red[threadIdx.x + off];
                if (o < red[threadIdx.x]) red[threadIdx.x] = o;
            }
            __syncthreads();
        }
        if (threadIdx.x == 0) atomicMin(&eslot[s], red[0]);
    }
}

__global__ __launch_bounds__(256) void exact_write_kernel(
    const int* __restrict__ flag2_cnt, const int* __restrict__ flag2_list,
    const u64* __restrict__ eslot, int* __restrict__ idx_i, float* __restrict__ idx_f)
{
    const int s = blockIdx.x * 256 + threadIdx.x;
    const int cnt = min(*flag2_cnt, CAPE);
    if (s >= cnt) return;
    const int n = flag2_list[s] & (N - 1);
    const int k = (int)(eslot[s] & (u64)(K - 1));
    idx_i[n] = k;
    idx_f[n] = (float)k;
}

// ---------------------------------------------------------------------------
__global__ __launch_bounds__(256) void count_kernel(
    const int* __restrict__ idx_i, int* __restrict__ cnti)
{
    const int p = blockIdx.x * 256 + threadIdx.x;
    atomicAdd(&cnti[idx_i[p] & (K - 1)], 1);
}

// ---------------------------------------------------------------------------
__global__ __launch_bounds__(256) void scan_kernel(
    const int* __restrict__ cnti, const float* __restrict__ csz,
    int* __restrict__ offs, int* __restrict__ nxt,
    float* __restrict__ ncs, double* __restrict__ n_sum)
{
    __shared__ int    tsum[256];
    __shared__ double dsum[256];
    const int t = threadIdx.x;
    const int base = t * 32;
    int s = 0;
    double dn = 0.0;
#pragma unroll
    for (int i = 0; i < 32; ++i) {
        const int c = cnti[base + i];
        s += c;
        const float v = DECAYF * csz[base + i] + OMDECAY * (float)c;
        ncs[base + i] = v;
        dn += (double)v;
    }
    tsum[t] = s; dsum[t] = dn;
    __syncthreads();
    int run = 0;
    for (int j = 0; j < t; ++j) run += tsum[j];
#pragma unroll
    for (int i = 0; i < 32; ++i) {
        offs[base + i] = run;
        nxt[base + i] = run;
        run += cnti[base + i];
    }
    if (t == 255) offs[K] = run;
    if (t == 0) {
        double tot = 0.0;
        for (int j = 0; j < 256; ++j) tot += dsum[j];
        n_sum[0] = tot;
    }
}

// ---------------------------------------------------------------------------
__global__ __launch_bounds__(256) void fill_kernel(
    const int* __restrict__ idx_i, int* __restrict__ nxt, int* __restrict__ list)
{
    const int p = blockIdx.x * 256 + threadIdx.x;
    const int k = idx_i[p] & (K - 1);
    const int pos = atomicAdd(&nxt[k], 1);
    if ((unsigned)pos < (unsigned)N) list[pos] = p;
}

// ---------------------------------------------------------------------------
__global__ __launch_bounds__(128) void gather_finalize_kernel(
    const float* __restrict__ x, const float* __restrict__ cb,
    const int* __restrict__ offs, const int* __restrict__ list,
    const float* __restrict__ ema_w, const float* __restrict__ ncs,
    const double* __restrict__ n_sum, float* __restrict__ new_ema,
    float* __restrict__ new_cb, float* __restrict__ zq,
    double* __restrict__ loss_part)
{
    const int k = blockIdx.x;
    const int t = threadIdx.x;
    const int beg = min(offs[k], N), end = min(offs[k + 1], N);
    const size_t o = (size_t)k * 128 + t;
    const float4 c = ((const float4*)cb)[o];
    float4 acc = {0.f, 0.f, 0.f, 0.f};
    float lsum = 0.f;
    for (int i = beg; i < end; ++i) {
        const int p = list[i] & (N - 1);
        const float4 v = ((const float4*)x)[(size_t)p * 128 + t];
        acc.x += v.x; acc.y += v.y; acc.z += v.z; acc.w += v.w;
        ((float4*)zq)[(size_t)p * 128 + t] = c;
        const float d0 = v.x - c.x, d1 = v.y - c.y, d2 = v.z - c.z, d3 = v.w - c.w;
        lsum += d0 * d0 + d1 * d1 + d2 * d2 + d3 * d3;
    }
    const float n = (float)n_sum[0];
    const float csm = (ncs[k] + EPSF) / (n + KEPSF) * n;
    const float4 e = ((const float4*)ema_w)[o];
    float4 ne;
    ne.x = DECAYF * e.x + OMDECAY * acc.x;
    ne.y = DECAYF * e.y + OMDECAY * acc.y;
    ne.z = DECAYF * e.z + OMDECAY * acc.z;
    ne.w = DECAYF * e.w + OMDECAY * acc.w;
    ((float4*)new_ema)[o] = ne;
    float4 nc;
    nc.x = ne.x / csm; nc.y = ne.y / csm; nc.z = ne.z / csm; nc.w = ne.w / csm;
    ((float4*)new_cb)[o] = nc;

#pragma unroll
    for (int m = 32; m >= 1; m >>= 1) lsum += __shfl_xor(lsum, m, 64);
    __shared__ float prt[2];
    if ((t & 63) == 0) prt[t >> 6] = lsum;
    __syncthreads();
    if (t == 0) loss_part[k] = (double)(prt[0] + prt[1]);
}

// ---------------------------------------------------------------------------
__global__ __launch_bounds__(256) void loss_reduce_kernel(
    const double* __restrict__ loss_part, float* __restrict__ out_loss)
{
    __shared__ double red[256];
    const int t = threadIdx.x;
    double s = 0.0;
    for (int i = t; i < K; i += 256) s += loss_part[i];
    red[t] = s;
    __syncthreads();
    for (int off = 128; off > 0; off >>= 1) {
        if (t < off) red[t] += red[t + off];
        __syncthreads();
    }
    if (t == 0)
        out_loss[0] = (float)(1.25 * (red[0] / (double)((size_t)N * D)));
}

// ---------------------------------------------------------------------------
extern "C" void kernel_launch(void* const* d_in, const int* in_sizes, int n_in,
                              void* d_out, int out_size, void* d_ws, size_t ws_size,
                              hipStream_t stream)
{
    const float* z_e   = (const float*)d_in[0];
    const float* cbook = (const float*)d_in[1];
    const float* csz   = (const float*)d_in[2];
    const float* ema_w = (const float*)d_in[3];

    float* out = (float*)d_out;
    u32*   ws  = (u32*)d_ws;

    float*  cnorm      = (float*)(ws + OFF_CNORM);
    int*    idx_i      = (int*)(ws + OFF_IDX);
    int*    cnti       = (int*)(ws + OFF_CNTI);
    int*    flag_cnt   = (int*)(ws + OFF_FLAGC);
    int*    flag2_cnt  = (int*)(ws + OFF_FLAG2C);
    int*    nxt        = (int*)(ws + OFF_NEXT);
    int*    offs       = (int*)(ws + OFF_OFFS);
    int*    list       = (int*)(ws + OFF_LIST);
    int*    flag_list  = (int*)(ws + OFF_FLAGL);
    int*    flag2_list = (int*)(ws + OFF_FLAG2L);
    float*  pb1        = (float*)(ws + OFF_PB1);
    float*  pb2        = (float*)(ws + OFF_PB2);
    int*    pi1        = (int*)(ws + OFF_PI1);
    u64*    eslot      = (u64*)(ws + OFF_ESLOT);
    double* n_sum      = (double*)(ws + OFF_SUMS);
    double* loss_part  = (double*)(ws + OFF_LOSSP);
    u16*    CBH        = (u16*)(ws + OFF_CBH);

    u16* XH  = (u16*)(out + XH_F);
    u16* PX2 = (u16*)(out + PX2_F);
    u16* CB2 = (u16*)(out + OUT_NCB);
    float* pb1h = out + PB1H_F;
    float* pb2h = out + PB2H_F;
    int*   pi1h = (int*)(out + PI1H_F);

    hipMemsetAsync(ws + OFF_CNTI, 0, (K + 2) * sizeof(u32), stream);
    hipMemsetAsync(ws + OFF_ESLOT, 0xFF, CAPE * sizeof(u64), stream);

    split_hi_kernel<<<N / 16, 256, 0, stream>>>(z_e, (u32x4*)XH);
    cbprep_kernel<<<K / 16, 256, 0, stream>>>(cbook, (u32x4*)CBH, (u32x4*)CB2, cnorm);

    argmin_hi_kernel<<<(N / BPH) * 4, 256, 0, stream>>>(CBH, XH, cnorm,
                                                        pb1h, pb2h, pi1h);

    merge_hi_kernel<<<N / 256, 256, 0, stream>>>(pb1h, pb2h, pi1h, idx_i,
                                                 out + OUT_IDX, flag_cnt, flag_list,
                                                 flag2_cnt, flag2_list);

    repack_kernel<<<CAP / 16, 256, 0, stream>>>(z_e, flag_cnt, flag_list, (u32x4*)PX2);

    argmin_part_kernel<<<(CAP / 128) * 16, 512, 0, stream>>>(CB2, PX2, cnorm, flag_cnt,
                                                             pb1, pb2, pi1);

    combine_kernel<<<CAP / 256, 256, 0, stream>>>(flag_cnt, flag_list, pb1, pb2, pi1,
                                                  idx_i, out + OUT_IDX,
                                                  flag2_cnt, flag2_list);

    exact_part_kernel<<<2048, 256, 0, stream>>>(z_e, cbook, cnorm, flag2_cnt,
                                                flag2_list, eslot);

    exact_write_kernel<<<CAPE / 256, 256, 0, stream>>>(flag2_cnt, flag2_list, eslot,
                                                       idx_i, out + OUT_IDX);

    count_kernel<<<N / 256, 256, 0, stream>>>(idx_i, cnti);

    scan_kernel<<<1, 256, 0, stream>>>(cnti, csz, offs, nxt, out + OUT_NCS, n_sum);

    fill_kernel<<<N / 256, 256, 0, stream>>>(idx_i, nxt, list);

    gather_finalize_kernel<<<K, 128, 0, stream>>>(z_e, cbook, offs, list, ema_w,
                                                  out + OUT_NCS, n_sum,
                                                  out + OUT_EMA, out + OUT_NCB,
                                                  out + OUT_ZQ, loss_part);

    loss_reduce_kernel<<<1, 256, 0, stream>>>(loss_part, out + OUT_LOSS);
}

// Round 15
// 855.990 us; speedup vs baseline: 1.0507x; 1.0507x over previous
//
#include <hip/hip_runtime.h>

// VQ-VAE EMA vector quantizer, MI355X.
// R15: argmin_hi = NO-LDS direct-to-register MFMA. Operands are already in
// fragment order in global memory -> each wave global_load_dwordx4's its
// af/bfr fragments directly (coalesced 1KB/instr), no staging, no barriers,
// waves fully independent. R14 evidence: staging rate scales with barrier
// domains (5.6->8.8 TB/s at 1->2 blocks/CU); removing the staging pipe
// entirely puts the argmin on the L2 roofline (6.4GB @ 34.5TB/s ~ 186us).
// All other kernels = R14.

constexpr int N = 32768;   // B*L
constexpr int D = 512;
constexpr int K = 8192;
constexpr int CAP  = 8192;
constexpr int CAPE = 4096;

constexpr float DECAYF  = 0.99f;
constexpr float OMDECAY = (float)(1.0 - 0.99);
constexpr float EPSF    = 1e-6f;
constexpr float KEPSF   = (float)(8192 * 1e-6);
constexpr float TAU1    = 1.0f;
constexpr float TAU2    = 0.02f;

typedef unsigned int       u32;
typedef unsigned short     u16;
typedef unsigned long long u64;
typedef float  f32x4 __attribute__((ext_vector_type(4)));
typedef u32    u32x4 __attribute__((ext_vector_type(4)));
typedef __bf16 bf16x8 __attribute__((ext_vector_type(8)));

#define AS1 __attribute__((address_space(1)))
#define AS3 __attribute__((address_space(3)))

// ---- workspace layout (32-bit word offsets) ----
constexpr size_t OFF_CNORM  = 0;                          // K f32
constexpr size_t OFF_IDX    = OFF_CNORM + K;              // N int
constexpr size_t OFF_CNTI   = OFF_IDX + N;                // K int
constexpr size_t OFF_FLAGC  = OFF_CNTI + K;               // 1 int
constexpr size_t OFF_FLAG2C = OFF_FLAGC + 1;              // 1 int
constexpr size_t OFF_NEXT   = OFF_FLAG2C + 1;             // K int
constexpr size_t OFF_OFFS   = OFF_NEXT + K;               // K+1 int
constexpr size_t OFF_LIST   = OFF_OFFS + K + 1;           // N int
constexpr size_t OFF_FLAGL  = OFF_LIST + N;               // CAP int
constexpr size_t OFF_FLAG2L = OFF_FLAGL + CAP;            // N int
constexpr size_t OFF_PB1    = OFF_FLAG2L + N;             // 16*CAP f32
constexpr size_t OFF_PB2    = OFF_PB1 + 16 * CAP;         // 16*CAP f32
constexpr size_t OFF_PI1    = OFF_PB2 + 16 * CAP;         // 16*CAP int
constexpr size_t OFF_ESLOT  = (OFF_PI1 + 16 * CAP + 1) & ~(size_t)1;
constexpr size_t OFF_SUMS   = (OFF_ESLOT + 2 * CAPE + 1) & ~(size_t)1;
constexpr size_t OFF_LOSSP  = (OFF_SUMS + 2 + 1) & ~(size_t)1;
constexpr size_t OFF_CBH    = (OFF_LOSSP + 2 * K + 3) & ~(size_t)3;
static_assert((OFF_ESLOT & 1) == 0 && (OFF_SUMS & 1) == 0 && (OFF_LOSSP & 1) == 0, "align");
static_assert((OFF_CBH & 3) == 0, "16B align");

// ---- output layout (float offsets) ----
constexpr size_t OUT_ZQ   = 0;
constexpr size_t OUT_IDX  = OUT_ZQ + (size_t)N * D;
constexpr size_t OUT_LOSS = OUT_IDX + N;
constexpr size_t OUT_NCB  = OUT_LOSS + 1;
constexpr size_t OUT_NCS  = OUT_NCB + (size_t)K * D;
constexpr size_t OUT_EMA  = OUT_NCS + K;
constexpr size_t XH_F  = OUT_ZQ;
constexpr size_t PX2_F = OUT_ZQ + (size_t)N * 256;
constexpr size_t PB1H_F = OUT_EMA;
constexpr size_t PB2H_F = OUT_EMA + 4 * (size_t)N;
constexpr size_t PI1H_F = OUT_EMA + 8 * (size_t)N;

// ---------------------------------------------------------------------------
__device__ inline u16 f32_to_bf16_rne(float f)
{
    u32 u = __builtin_bit_cast(u32, f);
    u = (u + 0x7FFFu + ((u >> 16) & 1u)) >> 16;
    return (u16)u;
}

// hi-only split of z_e: [rows/16][16 slices][64 lanes][8 u16]
__global__ __launch_bounds__(256) void split_hi_kernel(const float* __restrict__ src,
                                                       u32x4* __restrict__ dst)
{
    const int T = blockIdx.x;
    const int w = threadIdx.x >> 6;
    const int l = threadIdx.x & 63;
    const int row = T * 16 + (l & 15);
#pragma unroll
    for (int i = 0; i < 4; ++i) {
        const int S  = w * 4 + i;
        const int q4 = S * 8 + (l >> 4) * 2;
        const float4 va = ((const float4*)src)[(size_t)row * 128 + q4];
        const float4 vb = ((const float4*)src)[(size_t)row * 128 + q4 + 1];
        const float a[8] = {va.x, va.y, va.z, va.w, vb.x, vb.y, vb.z, vb.w};
        u32x4 o;
#pragma unroll
        for (int j = 0; j < 4; ++j)
            ((u32*)&o)[j] = (u32)f32_to_bf16_rne(a[2 * j]) |
                            ((u32)f32_to_bf16_rne(a[2 * j + 1]) << 16);
        dst[((size_t)T * 16 + S) * 64 + l] = o;
    }
}

// fused codebook prep: hi-split -> CBH, interleaved split -> CB2, norms -> cnorm
__global__ __launch_bounds__(256) void cbprep_kernel(const float* __restrict__ cb,
                                                     u32x4* __restrict__ CBH,
                                                     u32x4* __restrict__ CB2,
                                                     float* __restrict__ cnorm)
{
    const int T = blockIdx.x;
    const int w = threadIdx.x >> 6;
    const int l = threadIdx.x & 63;
    {
        const int row = T * 16 + (l & 15);
#pragma unroll
        for (int i = 0; i < 4; ++i) {
            const int S  = w * 4 + i;
            const int q4 = S * 8 + (l >> 4) * 2;
            const float4 va = ((const float4*)cb)[(size_t)row * 128 + q4];
            const float4 vb = ((const float4*)cb)[(size_t)row * 128 + q4 + 1];
            const float a[8] = {va.x, va.y, va.z, va.w, vb.x, vb.y, vb.z, vb.w};
            u32x4 o;
#pragma unroll
            for (int j = 0; j < 4; ++j)
                ((u32*)&o)[j] = (u32)f32_to_bf16_rne(a[2 * j]) |
                                ((u32)f32_to_bf16_rne(a[2 * j + 1]) << 16);
            CBH[((size_t)T * 16 + S) * 64 + l] = o;
        }
    }
    {
        const int row = T * 16 + (l & 15);
        const int cq  = l >> 4;
#pragma unroll
        for (int i = 0; i < 8; ++i) {
            const int S = w + 4 * i;
            const float4 v = ((const float4*)cb)[(size_t)row * 128 + S * 4 + cq];
            u32x4 o;
            const float a[4] = {v.x, v.y, v.z, v.w};
#pragma unroll
            for (int j = 0; j < 4; ++j) {
                const u16 hi = f32_to_bf16_rne(a[j]);
                const float hif = __builtin_bit_cast(float, (u32)hi << 16);
                const u16 lo = f32_to_bf16_rne(a[j] - hif);
                ((u32*)&o)[j] = (u32)hi | ((u32)lo << 16);
            }
            CB2[((size_t)T * 32 + S) * 64 + l] = o;
        }
    }
#pragma unroll
    for (int sub = 0; sub < 4; ++sub) {
        const int row = T * 16 + sub * 4 + w;
        const float4* r = (const float4*)(cb + (size_t)row * D);
        const float4 v0 = r[l];
        const float4 v1 = r[l + 64];
        float s = v0.x * v0.x + v0.y * v0.y + v0.z * v0.z + v0.w * v0.w
                + v1.x * v1.x + v1.y * v1.y + v1.z * v1.z + v1.w * v1.w;
#pragma unroll
        for (int m = 32; m >= 1; m >>= 1) s += __shfl_xor(s, m, 64);
        if (l == 0) cnorm[row] = s;
    }
}

// indirect split of flagged points -> PX2 interleaved frag order
__global__ __launch_bounds__(256) void repack_kernel(
    const float* __restrict__ z_e, const int* __restrict__ flag_cnt,
    const int* __restrict__ flag_list, u32x4* __restrict__ PX2)
{
    const int B = blockIdx.x;
    const int cnt = min(*flag_cnt, CAP);
    if (B * 16 >= cnt) return;
    const int w = threadIdx.x >> 6;
    const int l = threadIdx.x & 63;
    const int srow = B * 16 + (l & 15);
    const int n = (srow < cnt) ? (flag_list[srow] & (N - 1)) : 0;
    const int cq = l >> 4;
#pragma unroll
    for (int i = 0; i < 8; ++i) {
        const int S = w + 4 * i;
        const float4 v = ((const float4*)z_e)[(size_t)n * 128 + S * 4 + cq];
        u32x4 o;
        const float a[4] = {v.x, v.y, v.z, v.w};
#pragma unroll
        for (int j = 0; j < 4; ++j) {
            const u16 hi = f32_to_bf16_rne(a[j]);
            const float hif = __builtin_bit_cast(float, (u32)hi << 16);
            const u16 lo = f32_to_bf16_rne(a[j] - hif);
            ((u32*)&o)[j] = (u32)hi | ((u32)lo << 16);
        }
        PX2[((size_t)B * 32 + S) * 64 + l] = o;
    }
}

// ---------------------------------------------------------------------------
// Pass 1: hi-only argmin, NO-LDS direct-load. 256 thr (4 independent waves).
// Block: point-tile (128 pts) x K-quarter. Wave w: codes [q*2048+w*512, +512)
// as 8 chunks of 64; per k-step loads af[4]/bfr[8] fragments straight from
// global (fragment-order layout -> coalesced b128), MFMAs, no barriers.
constexpr int BPH = 128;

__global__ __launch_bounds__(256, 2) void argmin_hi_kernel(
    const u16* __restrict__ CBH, const u16* __restrict__ XH,
    const float* __restrict__ cnorm,
    float* __restrict__ pb1h, float* __restrict__ pb2h, int* __restrict__ pi1h)
{
    __shared__ float mb1[4 * BPH];
    __shared__ float mb2[4 * BPH];
    __shared__ int   mi [4 * BPH];

    const int b    = blockIdx.x;
    const int kq   = (b & 7) >> 1;               // K quarter (XCD-affine)
    const int n0   = ((b >> 3) * 2 + (b & 1)) * BPH;
    const int tid  = threadIdx.x;
    const int w    = tid >> 6;
    const int lane = tid & 63;
    const int lhi  = lane >> 4;

    // u16 bases: group stride 16*512=8192, slice stride 512
    const u16* cbase = CBH + ((size_t)(kq * 128 + w * 32) * 8192) + lane * 8;
    const u16* xbase = XH + ((size_t)(n0 / 16) * 8192) + lane * 8;

    float b1[8], b2[8]; int i1[8];
#pragma unroll
    for (int p = 0; p < 8; ++p) { b1[p] = INFINITY; b2[p] = INFINITY; i1[p] = 0; }

    for (int c = 0; c < 8; ++c) {               // 8 chunks of 64 codes
        f32x4 acc[4][8];
        const f32x4 zero = {0.f, 0.f, 0.f, 0.f};
#pragma unroll
        for (int cg = 0; cg < 4; ++cg)
#pragma unroll
            for (int p = 0; p < 8; ++p) acc[cg][p] = zero;

#pragma unroll 2
        for (int s = 0; s < 16; ++s) {
            u32x4 af[4], bfr[8];
#pragma unroll
            for (int cg = 0; cg < 4; ++cg)
                af[cg] = *(const u32x4*)(cbase + ((c * 4 + cg) * 16 + s) * 512);
#pragma unroll
            for (int p = 0; p < 8; ++p)
                bfr[p] = *(const u32x4*)(xbase + (p * 16 + s) * 512);
#pragma unroll
            for (int cg = 0; cg < 4; ++cg)
#pragma unroll
                for (int p = 0; p < 8; ++p)
                    acc[cg][p] = __builtin_amdgcn_mfma_f32_16x16x32_bf16(
                        __builtin_bit_cast(bf16x8, af[cg]),
                        __builtin_bit_cast(bf16x8, bfr[p]), acc[cg][p], 0, 0, 0);
        }

        const int cb0 = kq * 2048 + w * 512 + c * 64;
#pragma unroll
        for (int cg = 0; cg < 4; ++cg) {
            const int code0 = cb0 + cg * 16 + lhi * 4;
            const float4 cn4 = *(const float4*)(cnorm + code0);
            const float cn[4] = {cn4.x, cn4.y, cn4.z, cn4.w};
#pragma unroll
            for (int p = 0; p < 8; ++p) {
                const f32x4 A = acc[cg][p];
                const float dv[4] = {cn[0] - 2.f * A.x, cn[1] - 2.f * A.y,
                                     cn[2] - 2.f * A.z, cn[3] - 2.f * A.w};
#pragma unroll
                for (int r = 0; r < 4; ++r) {
                    if (dv[r] < b1[p]) { b2[p] = b1[p]; b1[p] = dv[r]; i1[p] = code0 + r; }
                    else if (dv[r] < b2[p]) { b2[p] = dv[r]; }
                }
            }
        }
    }

    // cross-lane merge (lanes {x, x+16, x+32, x+48} hold same point)
#pragma unroll
    for (int p = 0; p < 8; ++p) {
#pragma unroll
        for (int m = 16; m <= 32; m <<= 1) {
            const float ob1 = __shfl_xor(b1[p], m, 64);
            const float ob2 = __shfl_xor(b2[p], m, 64);
            const int   oi1 = __shfl_xor(i1[p], m, 64);
            const float nb2 = fminf(fminf(b2[p], ob2), fmaxf(b1[p], ob1));
            if (ob1 < b1[p] || (ob1 == b1[p] && oi1 < i1[p])) { b1[p] = ob1; i1[p] = oi1; }
            b2[p] = nb2;
        }
    }

    if (lane < 16) {
#pragma unroll
        for (int p = 0; p < 8; ++p) {
            const int pt = p * 16 + lane;
            mb1[w * BPH + pt] = b1[p];
            mb2[w * BPH + pt] = b2[p];
            mi [w * BPH + pt] = i1[p];
        }
    }
    __syncthreads();
    if (tid < BPH) {
        float fb1 = INFINITY, fb2 = INFINITY; int fi = 0;
        for (int ww = 0; ww < 4; ++ww) {       // ascending ww = ascending codes
            const float a1 = mb1[ww * BPH + tid], a2 = mb2[ww * BPH + tid];
            const int   ai = mi[ww * BPH + tid];
            const float nb2 = fminf(fminf(fb2, a2), fmaxf(fb1, a1));
            if (a1 < fb1 || (a1 == fb1 && ai < fi)) { fb1 = a1; fi = ai; }
            fb2 = nb2;
        }
        const int n = n0 + tid;
        pb1h[kq * N + n] = fb1;
        pb2h[kq * N + n] = fb2;
        pi1h[kq * N + n] = fi;
    }
}

// ---------------------------------------------------------------------------
__global__ __launch_bounds__(256) void merge_hi_kernel(
    const float* __restrict__ pb1h, const float* __restrict__ pb2h,
    const int* __restrict__ pi1h,
    int* __restrict__ idx_i, float* __restrict__ idx_f,
    int* __restrict__ flag_cnt, int* __restrict__ flag_list,
    int* __restrict__ flag2_cnt, int* __restrict__ flag2_list)
{
    const int n = blockIdx.x * 256 + threadIdx.x;
    float fb1 = INFINITY, fb2 = INFINITY; int fi = 0x7fffffff;
#pragma unroll
    for (int q = 0; q < 4; ++q) {
        const float a1 = pb1h[q * N + n], a2 = pb2h[q * N + n];
        const int   ai = pi1h[q * N + n];
        const float nb2 = fminf(fminf(fb2, a2), fmaxf(fb1, a1));
        if (a1 < fb1 || (a1 == fb1 && ai < fi)) { fb1 = a1; fi = ai; }
        fb2 = nb2;
    }
    idx_i[n] = fi;
    idx_f[n] = (float)fi;
    if (fb2 - fb1 < TAU1) {
        const int pos = atomicAdd(flag_cnt, 1);
        if (pos < CAP) flag_list[pos] = n;
        else {
            const int p2 = atomicAdd(flag2_cnt, 1);
            if ((unsigned)p2 < (unsigned)N) flag2_list[p2] = n;
        }
    }
}

// ---------------------------------------------------------------------------
// Pass 2: split-precision argmin, ONE 512-code chunk per block.
constexpr int CEL2 = 512 * 32;
constexpr int XEL2 = 128 * 32;
constexpr int BUF2 = CEL2 + XEL2;

__global__ __launch_bounds__(512, 2) void argmin_part_kernel(
    const u16* __restrict__ CB2, const u16* __restrict__ PX2,
    const float* __restrict__ cnorm, const int* __restrict__ flag_cnt,
    float* __restrict__ pb1, float* __restrict__ pb2, int* __restrict__ pi1)
{
    const int q  = blockIdx.x & 15;
    const int sb = blockIdx.x >> 4;
    const int cnt = min(*flag_cnt, CAP);
    if (sb * 128 >= cnt) return;
    const int n0s = sb * 128;

    __shared__ __align__(16) u16 lds[2][BUF2];

    const int tid  = threadIdx.x;
    const int w    = tid >> 6;
    const int lane = tid & 63;
    const int lhi  = lane >> 4;

    auto stage = [&](u16* bufp, int s) {
#pragma unroll
        for (int j = 0; j < 4; ++j) {
            const int slot = j * 512 + tid;
            const u16* gsrc = CB2 + (((size_t)(q * 32 + (slot >> 6)) * 32 + s) * 512
                                     + (slot & 63) * 8);
            __builtin_amdgcn_global_load_lds((const AS1 u32*)gsrc,
                                             (AS3 u32*)(bufp + slot * 8), 16, 0, 0);
        }
        const u16* gx = PX2 + (((size_t)(n0s / 16 + (tid >> 6)) * 32 + s) * 512
                               + (tid & 63) * 8);
        __builtin_amdgcn_global_load_lds((const AS1 u32*)gx,
                                         (AS3 u32*)(bufp + CEL2 + tid * 8), 16, 0, 0);
    };

    float b1[8], b2[8]; int i1[8];
#pragma unroll
    for (int p = 0; p < 8; ++p) { b1[p] = INFINITY; b2[p] = INFINITY; i1[p] = 0; }

    f32x4 acc[4][8];
    const f32x4 zero = {0.f, 0.f, 0.f, 0.f};
#pragma unroll
    for (int cg = 0; cg < 4; ++cg)
#pragma unroll
        for (int p = 0; p < 8; ++p) acc[cg][p] = zero;

    stage(&lds[0][0], 0);
    __syncthreads();

#pragma unroll 2
    for (int s = 0; s < 32; ++s) {
        const u16* cur = (s & 1) ? &lds[1][0] : &lds[0][0];
        u16* nxt       = (s & 1) ? &lds[0][0] : &lds[1][0];
        if (s + 1 < 32) stage(nxt, s + 1);

        u32x4 bfr[8];
#pragma unroll
        for (int p = 0; p < 8; ++p)
            bfr[p] = *(const u32x4*)(cur + CEL2 + p * 512 + lane * 8);
#pragma unroll
        for (int cg = 0; cg < 4; ++cg) {
            const u32x4 af = *(const u32x4*)(cur + (w * 4 + cg) * 512 + lane * 8);
            u32x4 as;
            as.x = (af.x >> 16) | (af.x << 16);
            as.y = (af.y >> 16) | (af.y << 16);
            as.z = (af.z >> 16) | (af.z << 16);
            as.w = (af.w >> 16) | (af.w << 16);
#pragma unroll
            for (int p = 0; p < 8; ++p) {
                acc[cg][p] = __builtin_amdgcn_mfma_f32_16x16x32_bf16(
                    __builtin_bit_cast(bf16x8, af), __builtin_bit_cast(bf16x8, bfr[p]),
                    acc[cg][p], 0, 0, 0);
                acc[cg][p] = __builtin_amdgcn_mfma_f32_16x16x32_bf16(
                    __builtin_bit_cast(bf16x8, as), __builtin_bit_cast(bf16x8, bfr[p]),
                    acc[cg][p], 0, 0, 0);
            }
        }
        __syncthreads();
    }

    const int cb0 = q * 512 + w * 64;
#pragma unroll
    for (int cg = 0; cg < 4; ++cg) {
        const int code0 = cb0 + cg * 16 + lhi * 4;
        const float4 cn4 = *(const float4*)(cnorm + code0);
        const float cn[4] = {cn4.x, cn4.y, cn4.z, cn4.w};
#pragma unroll
        for (int p = 0; p < 8; ++p) {
            const f32x4 A = acc[cg][p];
            const float dv[4] = {cn[0] - 2.f * A.x, cn[1] - 2.f * A.y,
                                 cn[2] - 2.f * A.z, cn[3] - 2.f * A.w};
#pragma unroll
            for (int r = 0; r < 4; ++r) {
                if (dv[r] < b1[p]) { b2[p] = b1[p]; b1[p] = dv[r]; i1[p] = code0 + r; }
                else if (dv[r] < b2[p]) { b2[p] = dv[r]; }
            }
        }
    }

#pragma unroll
    for (int p = 0; p < 8; ++p) {
#pragma unroll
        for (int m = 16; m <= 32; m <<= 1) {
            const float ob1 = __shfl_xor(b1[p], m, 64);
            const float ob2 = __shfl_xor(b2[p], m, 64);
            const int   oi1 = __shfl_xor(i1[p], m, 64);
            const float nb2 = fminf(fminf(b2[p], ob2), fmaxf(b1[p], ob1));
            if (ob1 < b1[p] || (ob1 == b1[p] && oi1 < i1[p])) { b1[p] = ob1; i1[p] = oi1; }
            b2[p] = nb2;
        }
    }

    __syncthreads();

    float* mb1 = (float*)&lds[0][0];
    float* mb2 = mb1 + 8 * 128;
    int*   mi  = (int*)(mb2 + 8 * 128);
    if (lane < 16) {
#pragma unroll
        for (int p = 0; p < 8; ++p) {
            const int pt = p * 16 + lane;
            mb1[w * 128 + pt] = b1[p];
            mb2[w * 128 + pt] = b2[p];
            mi [w * 128 + pt] = i1[p];
        }
    }
    __syncthreads();
    if (tid < 128) {
        float fb1 = INFINITY, fb2 = INFINITY; int fi = 0;
        for (int ww = 0; ww < 8; ++ww) {
            const float a1 = mb1[ww * 128 + tid], a2 = mb2[ww * 128 + tid];
            const int   ai = mi[ww * 128 + tid];
            const float nb2 = fminf(fminf(fb2, a2), fmaxf(fb1, a1));
            if (a1 < fb1 || (a1 == fb1 && ai < fi)) { fb1 = a1; fi = ai; }
            fb2 = nb2;
        }
        const int slot = n0s + tid;
        pb1[q * CAP + slot] = fb1;
        pb2[q * CAP + slot] = fb2;
        pi1[q * CAP + slot] = fi;
    }
}

// ---------------------------------------------------------------------------
__global__ __launch_bounds__(256) void combine_kernel(
    const int* __restrict__ flag_cnt, const int* __restrict__ flag_list,
    const float* __restrict__ pb1, const float* __restrict__ pb2,
    const int* __restrict__ pi1,
    int* __restrict__ idx_i, float* __restrict__ idx_f,
    int* __restrict__ flag2_cnt, int* __restrict__ flag2_list)
{
    const int s = blockIdx.x * 256 + threadIdx.x;
    const int cnt = min(*flag_cnt, CAP);
    if (s >= cnt) return;
    float fb1 = INFINITY, fb2 = INFINITY; int fi = 0x7fffffff;
#pragma unroll
    for (int q = 0; q < 16; ++q) {
        const float a1 = pb1[q * CAP + s], a2 = pb2[q * CAP + s];
        const int   ai = pi1[q * CAP + s];
        const float nb2 = fminf(fminf(fb2, a2), fmaxf(fb1, a1));
        if (a1 < fb1 || (a1 == fb1 && ai < fi)) { fb1 = a1; fi = ai; }
        fb2 = nb2;
    }
    const int n = flag_list[s] & (N - 1);
    idx_i[n] = fi;
    idx_f[n] = (float)fi;
    if (fb2 - fb1 < TAU2) {
        const int p2 = atomicAdd(flag2_cnt, 1);
        if ((unsigned)p2 < (unsigned)N) flag2_list[p2] = n;
    }
}

// ---------------------------------------------------------------------------
__global__ __launch_bounds__(256) void exact_part_kernel(
    const float* __restrict__ x, const float* __restrict__ cb,
    const float* __restrict__ cnorm, const int* __restrict__ flag2_cnt,
    const int* __restrict__ flag2_list, u64* __restrict__ eslot)
{
    __shared__ float4 xs[128];
    __shared__ u64 red[256];
    const int cnt = min(*flag2_cnt, CAPE);
    const int nwork = cnt * 16;
    for (int j = blockIdx.x; j < nwork; j += gridDim.x) {
        const int s = j >> 4;
        const int q = j & 15;
        const int n = flag2_list[s] & (N - 1);
        __syncthreads();
        if (threadIdx.x < 128)
            xs[threadIdx.x] = ((const float4*)(x + (size_t)n * D))[threadIdx.x];
        __syncthreads();
        u64 bestp = ~0ull;
#pragma unroll
        for (int c = 0; c < 2; ++c) {
            const int k = q * 512 + c * 256 + threadIdx.x;
            const float4* crow = (const float4*)(cb + (size_t)k * D);
            float a0 = 0.f, a1 = 0.f, a2 = 0.f, a3 = 0.f;
            for (int d = 0; d < 128; ++d) {
                const float4 xv = xs[d], cv = crow[d];
                a0 = fmaf(xv.x, cv.x, a0);
                a1 = fmaf(xv.y, cv.y, a1);
                a2 = fmaf(xv.z, cv.z, a2);
                a3 = fmaf(xv.w, cv.w, a3);
            }
            const float dist = cnorm[k] - 2.0f * ((a0 + a1) + (a2 + a3));
            u32 ub = __builtin_bit_cast(u32, dist);
            ub = (ub & 0x80000000u) ? ~ub : (ub | 0x80000000u);
            const u64 pk = ((u64)ub << 32) | (u32)k;
            bestp = bestp < pk ? bestp : pk;
        }
        red[threadIdx.x] = bestp;
        __syncthreads();
        for (int off = 128; off > 0; off >>= 1) {
            if (threadIdx.x < off) {
                const u64 o = red[threadIdx.x + off];
                if (o < red[threadIdx.x]) red[threadIdx.x] = o;
            }
            __syncthreads();
        }
        if (threadIdx.x == 0) atomicMin(&eslot[s], red[0]);
    }
}

__global__ __launch_bounds__(256) void exact_write_kernel(
    const int* __restrict__ flag2_cnt, const int* __restrict__ flag2_list,
    const u64* __restrict__ eslot, int* __restrict__ idx_i, float* __restrict__ idx_f)
{
    const int s = blockIdx.x * 256 + threadIdx.x;
    const int cnt = min(*flag2_cnt, CAPE);
    if (s >= cnt) return;
    const int n = flag2_list[s] & (N - 1);
    const int k = (int)(eslot[s] & (u64)(K - 1));
    idx_i[n] = k;
    idx_f[n] = (float)k;
}

// ---------------------------------------------------------------------------
__global__ __launch_bounds__(256) void count_kernel(
    const int* __restrict__ idx_i, int* __restrict__ cnti)
{
    const int p = blockIdx.x * 256 + threadIdx.x;
    atomicAdd(&cnti[idx_i[p] & (K - 1)], 1);
}

// ---------------------------------------------------------------------------
__global__ __launch_bounds__(256) void scan_kernel(
    const int* __restrict__ cnti, const float* __restrict__ csz,
    int* __restrict__ offs, int* __restrict__ nxt,
    float* __restrict__ ncs, double* __restrict__ n_sum)
{
    __shared__ int    tsum[256];
    __shared__ double dsum[256];
    const int t = threadIdx.x;
    const int base = t * 32;
    int s = 0;
    double dn = 0.0;
#pragma unroll
    for (int i = 0; i < 32; ++i) {
        const int c = cnti[base + i];
        s += c;
        const float v = DECAYF * csz[base + i] + OMDECAY * (float)c;
        ncs[base + i] = v;
        dn += (double)v;
    }
    tsum[t] = s; dsum[t] = dn;
    __syncthreads();
    int run = 0;
    for (int j = 0; j < t; ++j) run += tsum[j];
#pragma unroll
    for (int i = 0; i < 32; ++i) {
        offs[base + i] = run;
        nxt[base + i] = run;
        run += cnti[base + i];
    }
    if (t == 255) offs[K] = run;
    if (t == 0) {
        double tot = 0.0;
        for (int j = 0; j < 256; ++j) tot += dsum[j];
        n_sum[0] = tot;
    }
}

// ---------------------------------------------------------------------------
__global__ __launch_bounds__(256) void fill_kernel(
    const int* __restrict__ idx_i, int* __restrict__ nxt, int* __restrict__ list)
{
    const int p = blockIdx.x * 256 + threadIdx.x;
    const int k = idx_i[p] & (K - 1);
    const int pos = atomicAdd(&nxt[k], 1);
    if ((unsigned)pos < (unsigned)N) list[pos] = p;
}

// ---------------------------------------------------------------------------
__global__ __launch_bounds__(128) void gather_finalize_kernel(
    const float* __restrict__ x, const float* __restrict__ cb,
    const int* __restrict__ offs, const int* __restrict__ list,
    const float* __restrict__ ema_w, const float* __restrict__ ncs,
    const double* __restrict__ n_sum, float* __restrict__ new_ema,
    float* __restrict__ new_cb, float* __restrict__ zq,
    double* __restrict__ loss_part)
{
    const int k = blockIdx.x;
    const int t = threadIdx.x;
    const int beg = min(offs[k], N), end = min(offs[k + 1], N);
    const size_t o = (size_t)k * 128 + t;
    const float4 c = ((const float4*)cb)[o];
    float4 acc = {0.f, 0.f, 0.f, 0.f};
    float lsum = 0.f;
    for (int i = beg; i < end; ++i) {
        const int p = list[i] & (N - 1);
        const float4 v = ((const float4*)x)[(size_t)p * 128 + t];
        acc.x += v.x; acc.y += v.y; acc.z += v.z; acc.w += v.w;
        ((float4*)zq)[(size_t)p * 128 + t] = c;
        const float d0 = v.x - c.x, d1 = v.y - c.y, d2 = v.z - c.z, d3 = v.w - c.w;
        lsum += d0 * d0 + d1 * d1 + d2 * d2 + d3 * d3;
    }
    const float n = (float)n_sum[0];
    const float csm = (ncs[k] + EPSF) / (n + KEPSF) * n;
    const float4 e = ((const float4*)ema_w)[o];
    float4 ne;
    ne.x = DECAYF * e.x + OMDECAY * acc.x;
    ne.y = DECAYF * e.y + OMDECAY * acc.y;
    ne.z = DECAYF * e.z + OMDECAY * acc.z;
    ne.w = DECAYF * e.w + OMDECAY * acc.w;
    ((float4*)new_ema)[o] = ne;
    float4 nc;
    nc.x = ne.x / csm; nc.y = ne.y / csm; nc.z = ne.z / csm; nc.w = ne.w / csm;
    ((float4*)new_cb)[o] = nc;

#pragma unroll
    for (int m = 32; m >= 1; m >>= 1) lsum += __shfl_xor(lsum, m, 64);
    __shared__ float prt[2];
    if ((t & 63) == 0) prt[t >> 6] = lsum;
    __syncthreads();
    if (t == 0) loss_part[k] = (double)(prt[0] + prt[1]);
}

// ---------------------------------------------------------------------------
__global__ __launch_bounds__(256) void loss_reduce_kernel(
    const double* __restrict__ loss_part, float* __restrict__ out_loss)
{
    __shared__ double red[256];
    const int t = threadIdx.x;
    double s = 0.0;
    for (int i = t; i < K; i += 256) s += loss_part[i];
    red[t] = s;
    __syncthreads();
    for (int off = 128; off > 0; off >>= 1) {
        if (t < off) red[t] += red[t + off];
        __syncthreads();
    }
    if (t == 0)
        out_loss[0] = (float)(1.25 * (red[0] / (double)((size_t)N * D)));
}

// ---------------------------------------------------------------------------
extern "C" void kernel_launch(void* const* d_in, const int* in_sizes, int n_in,
                              void* d_out, int out_size, void* d_ws, size_t ws_size,
                              hipStream_t stream)
{
    const float* z_e   = (const float*)d_in[0];
    const float* cbook = (const float*)d_in[1];
    const float* csz   = (const float*)d_in[2];
    const float* ema_w = (const float*)d_in[3];

    float* out = (float*)d_out;
    u32*   ws  = (u32*)d_ws;

    float*  cnorm      = (float*)(ws + OFF_CNORM);
    int*    idx_i      = (int*)(ws + OFF_IDX);
    int*    cnti       = (int*)(ws + OFF_CNTI);
    int*    flag_cnt   = (int*)(ws + OFF_FLAGC);
    int*    flag2_cnt  = (int*)(ws + OFF_FLAG2C);
    int*    nxt        = (int*)(ws + OFF_NEXT);
    int*    offs       = (int*)(ws + OFF_OFFS);
    int*    list       = (int*)(ws + OFF_LIST);
    int*    flag_list  = (int*)(ws + OFF_FLAGL);
    int*    flag2_list = (int*)(ws + OFF_FLAG2L);
    float*  pb1        = (float*)(ws + OFF_PB1);
    float*  pb2        = (float*)(ws + OFF_PB2);
    int*    pi1        = (int*)(ws + OFF_PI1);
    u64*    eslot      = (u64*)(ws + OFF_ESLOT);
    double* n_sum      = (double*)(ws + OFF_SUMS);
    double* loss_part  = (double*)(ws + OFF_LOSSP);
    u16*    CBH        = (u16*)(ws + OFF_CBH);

    u16* XH  = (u16*)(out + XH_F);
    u16* PX2 = (u16*)(out + PX2_F);
    u16* CB2 = (u16*)(out + OUT_NCB);
    float* pb1h = out + PB1H_F;
    float* pb2h = out + PB2H_F;
    int*   pi1h = (int*)(out + PI1H_F);

    hipMemsetAsync(ws + OFF_CNTI, 0, (K + 2) * sizeof(u32), stream);
    hipMemsetAsync(ws + OFF_ESLOT, 0xFF, CAPE * sizeof(u64), stream);

    split_hi_kernel<<<N / 16, 256, 0, stream>>>(z_e, (u32x4*)XH);
    cbprep_kernel<<<K / 16, 256, 0, stream>>>(cbook, (u32x4*)CBH, (u32x4*)CB2, cnorm);

    argmin_hi_kernel<<<(N / BPH) * 4, 256, 0, stream>>>(CBH, XH, cnorm,
                                                        pb1h, pb2h, pi1h);

    merge_hi_kernel<<<N / 256, 256, 0, stream>>>(pb1h, pb2h, pi1h, idx_i,
                                                 out + OUT_IDX, flag_cnt, flag_list,
                                                 flag2_cnt, flag2_list);

    repack_kernel<<<CAP / 16, 256, 0, stream>>>(z_e, flag_cnt, flag_list, (u32x4*)PX2);

    argmin_part_kernel<<<(CAP / 128) * 16, 512, 0, stream>>>(CB2, PX2, cnorm, flag_cnt,
                                                             pb1, pb2, pi1);

    combine_kernel<<<CAP / 256, 256, 0, stream>>>(flag_cnt, flag_list, pb1, pb2, pi1,
                                                  idx_i, out + OUT_IDX,
                                                  flag2_cnt, flag2_list);

    exact_part_kernel<<<2048, 256, 0, stream>>>(z_e, cbook, cnorm, flag2_cnt,
                                                flag2_list, eslot);

    exact_write_kernel<<<CAPE / 256, 256, 0, stream>>>(flag2_cnt, flag2_list, eslot,
                                                       idx_i, out + OUT_IDX);

    count_kernel<<<N / 256, 256, 0, stream>>>(idx_i, cnti);

    scan_kernel<<<1, 256, 0, stream>>>(cnti, csz, offs, nxt, out + OUT_NCS, n_sum);

    fill_kernel<<<N / 256, 256, 0, stream>>>(idx_i, nxt, list);

    gather_finalize_kernel<<<K, 128, 0, stream>>>(z_e, cbook, offs, list, ema_w,
                                                  out + OUT_NCS, n_sum,
                                                  out + OUT_EMA, out + OUT_NCB,
                                                  out + OUT_ZQ, loss_part);

    loss_reduce_kernel<<<1, 256, 0, stream>>>(loss_part, out + OUT_LOSS);
}

// Round 16
// 754.765 us; speedup vs baseline: 1.1916x; 1.1341x over previous
//
#include <hip/hip_runtime.h>

// VQ-VAE EMA vector quantizer, MI355X.
// R16: consolidation. argmin_hi = R13's exact kernel (best of 6 structures:
// 456us; bytes-x-rate invariant ~460us established R10-R15). Tail attack via
// flag arithmetic: TAU2 0.02->0.005 (exact_part reads 16MB/point; was ~80
// points ~ 200us), TAU1 1.0->0.7. cbprep fused (R14/R15 proven).

constexpr int N = 32768;   // B*L
constexpr int D = 512;
constexpr int K = 8192;
constexpr int CAP  = 8192;
constexpr int CAPE = 4096;

constexpr float DECAYF  = 0.99f;
constexpr float OMDECAY = (float)(1.0 - 0.99);
constexpr float EPSF    = 1e-6f;
constexpr float KEPSF   = (float)(8192 * 1e-6);
constexpr float TAU1    = 0.7f;     // hi-only gap threshold (~10 sigma of err-diff)
constexpr float TAU2    = 0.005f;   // split-precision gap threshold (>=5 sigma)

typedef unsigned int       u32;
typedef unsigned short     u16;
typedef unsigned long long u64;
typedef float  f32x4 __attribute__((ext_vector_type(4)));
typedef u32    u32x4 __attribute__((ext_vector_type(4)));
typedef __bf16 bf16x8 __attribute__((ext_vector_type(8)));

#define AS1 __attribute__((address_space(1)))
#define AS3 __attribute__((address_space(3)))

// ---- workspace layout (32-bit word offsets) ----
constexpr size_t OFF_CNORM  = 0;                          // K f32
constexpr size_t OFF_IDX    = OFF_CNORM + K;              // N int
constexpr size_t OFF_CNTI   = OFF_IDX + N;                // K int
constexpr size_t OFF_FLAGC  = OFF_CNTI + K;               // 1 int
constexpr size_t OFF_FLAG2C = OFF_FLAGC + 1;              // 1 int
constexpr size_t OFF_NEXT   = OFF_FLAG2C + 1;             // K int
constexpr size_t OFF_OFFS   = OFF_NEXT + K;               // K+1 int
constexpr size_t OFF_LIST   = OFF_OFFS + K + 1;           // N int
constexpr size_t OFF_FLAGL  = OFF_LIST + N;               // CAP int
constexpr size_t OFF_FLAG2L = OFF_FLAGL + CAP;            // N int
constexpr size_t OFF_PB1    = OFF_FLAG2L + N;             // 16*CAP f32
constexpr size_t OFF_PB2    = OFF_PB1 + 16 * CAP;         // 16*CAP f32
constexpr size_t OFF_PI1    = OFF_PB2 + 16 * CAP;         // 16*CAP int
constexpr size_t OFF_ESLOT  = (OFF_PI1 + 16 * CAP + 1) & ~(size_t)1;
constexpr size_t OFF_SUMS   = (OFF_ESLOT + 2 * CAPE + 1) & ~(size_t)1;
constexpr size_t OFF_LOSSP  = (OFF_SUMS + 2 + 1) & ~(size_t)1;
constexpr size_t OFF_CBH    = (OFF_LOSSP + 2 * K + 3) & ~(size_t)3;
static_assert((OFF_ESLOT & 1) == 0 && (OFF_SUMS & 1) == 0 && (OFF_LOSSP & 1) == 0, "align");
static_assert((OFF_CBH & 3) == 0, "16B align");

// ---- output layout (float offsets) ----
constexpr size_t OUT_ZQ   = 0;
constexpr size_t OUT_IDX  = OUT_ZQ + (size_t)N * D;
constexpr size_t OUT_LOSS = OUT_IDX + N;
constexpr size_t OUT_NCB  = OUT_LOSS + 1;
constexpr size_t OUT_NCS  = OUT_NCB + (size_t)K * D;
constexpr size_t OUT_EMA  = OUT_NCS + K;
constexpr size_t XH_F  = OUT_ZQ;
constexpr size_t PX2_F = OUT_ZQ + (size_t)N * 256;
constexpr size_t PB1H_F = OUT_EMA;
constexpr size_t PB2H_F = OUT_EMA + 4 * (size_t)N;
constexpr size_t PI1H_F = OUT_EMA + 8 * (size_t)N;

// ---------------------------------------------------------------------------
__device__ inline u16 f32_to_bf16_rne(float f)
{
    u32 u = __builtin_bit_cast(u32, f);
    u = (u + 0x7FFFu + ((u >> 16) & 1u)) >> 16;
    return (u16)u;
}

// hi-only split of z_e: [rows/16][16 slices][64 lanes][8 u16]
__global__ __launch_bounds__(256) void split_hi_kernel(const float* __restrict__ src,
                                                       u32x4* __restrict__ dst)
{
    const int T = blockIdx.x;
    const int w = threadIdx.x >> 6;
    const int l = threadIdx.x & 63;
    const int row = T * 16 + (l & 15);
#pragma unroll
    for (int i = 0; i < 4; ++i) {
        const int S  = w * 4 + i;
        const int q4 = S * 8 + (l >> 4) * 2;
        const float4 va = ((const float4*)src)[(size_t)row * 128 + q4];
        const float4 vb = ((const float4*)src)[(size_t)row * 128 + q4 + 1];
        const float a[8] = {va.x, va.y, va.z, va.w, vb.x, vb.y, vb.z, vb.w};
        u32x4 o;
#pragma unroll
        for (int j = 0; j < 4; ++j)
            ((u32*)&o)[j] = (u32)f32_to_bf16_rne(a[2 * j]) |
                            ((u32)f32_to_bf16_rne(a[2 * j + 1]) << 16);
        dst[((size_t)T * 16 + S) * 64 + l] = o;
    }
}

// fused codebook prep: hi-split -> CBH, interleaved split -> CB2, norms -> cnorm
__global__ __launch_bounds__(256) void cbprep_kernel(const float* __restrict__ cb,
                                                     u32x4* __restrict__ CBH,
                                                     u32x4* __restrict__ CB2,
                                                     float* __restrict__ cnorm)
{
    const int T = blockIdx.x;
    const int w = threadIdx.x >> 6;
    const int l = threadIdx.x & 63;
    {
        const int row = T * 16 + (l & 15);
#pragma unroll
        for (int i = 0; i < 4; ++i) {
            const int S  = w * 4 + i;
            const int q4 = S * 8 + (l >> 4) * 2;
            const float4 va = ((const float4*)cb)[(size_t)row * 128 + q4];
            const float4 vb = ((const float4*)cb)[(size_t)row * 128 + q4 + 1];
            const float a[8] = {va.x, va.y, va.z, va.w, vb.x, vb.y, vb.z, vb.w};
            u32x4 o;
#pragma unroll
            for (int j = 0; j < 4; ++j)
                ((u32*)&o)[j] = (u32)f32_to_bf16_rne(a[2 * j]) |
                                ((u32)f32_to_bf16_rne(a[2 * j + 1]) << 16);
            CBH[((size_t)T * 16 + S) * 64 + l] = o;
        }
    }
    {
        const int row = T * 16 + (l & 15);
        const int cq  = l >> 4;
#pragma unroll
        for (int i = 0; i < 8; ++i) {
            const int S = w + 4 * i;
            const float4 v = ((const float4*)cb)[(size_t)row * 128 + S * 4 + cq];
            u32x4 o;
            const float a[4] = {v.x, v.y, v.z, v.w};
#pragma unroll
            for (int j = 0; j < 4; ++j) {
                const u16 hi = f32_to_bf16_rne(a[j]);
                const float hif = __builtin_bit_cast(float, (u32)hi << 16);
                const u16 lo = f32_to_bf16_rne(a[j] - hif);
                ((u32*)&o)[j] = (u32)hi | ((u32)lo << 16);
            }
            CB2[((size_t)T * 32 + S) * 64 + l] = o;
        }
    }
#pragma unroll
    for (int sub = 0; sub < 4; ++sub) {
        const int row = T * 16 + sub * 4 + w;
        const float4* r = (const float4*)(cb + (size_t)row * D);
        const float4 v0 = r[l];
        const float4 v1 = r[l + 64];
        float s = v0.x * v0.x + v0.y * v0.y + v0.z * v0.z + v0.w * v0.w
                + v1.x * v1.x + v1.y * v1.y + v1.z * v1.z + v1.w * v1.w;
#pragma unroll
        for (int m = 32; m >= 1; m >>= 1) s += __shfl_xor(s, m, 64);
        if (l == 0) cnorm[row] = s;
    }
}

// indirect split of flagged points -> PX2 interleaved frag order
__global__ __launch_bounds__(256) void repack_kernel(
    const float* __restrict__ z_e, const int* __restrict__ flag_cnt,
    const int* __restrict__ flag_list, u32x4* __restrict__ PX2)
{
    const int B = blockIdx.x;
    const int cnt = min(*flag_cnt, CAP);
    if (B * 16 >= cnt) return;
    const int w = threadIdx.x >> 6;
    const int l = threadIdx.x & 63;
    const int srow = B * 16 + (l & 15);
    const int n = (srow < cnt) ? (flag_list[srow] & (N - 1)) : 0;
    const int cq = l >> 4;
#pragma unroll
    for (int i = 0; i < 8; ++i) {
        const int S = w + 4 * i;
        const float4 v = ((const float4*)z_e)[(size_t)n * 128 + S * 4 + cq];
        u32x4 o;
        const float a[4] = {v.x, v.y, v.z, v.w};
#pragma unroll
        for (int j = 0; j < 4; ++j) {
            const u16 hi = f32_to_bf16_rne(a[j]);
            const float hif = __builtin_bit_cast(float, (u32)hi << 16);
            const u16 lo = f32_to_bf16_rne(a[j] - hif);
            ((u32*)&o)[j] = (u32)hi | ((u32)lo << 16);
        }
        PX2[((size_t)B * 32 + S) * 64 + l] = o;
    }
}

// ---------------------------------------------------------------------------
// Pass 1: hi-only argmin (R13's kernel: K-quarter split, 80KB LDS, KI=32,
// incremental u32 offsets, per-quarter partials).
constexpr int BPH = 128, BCH = 512, KIH = 32;
constexpr int NSTEPH = 16;                 // slices per chunk
constexpr int NCHQ   = 4;                  // chunks per quarter
constexpr int TOTQ   = NCHQ * NSTEPH;      // 64 steps/block
constexpr int CELH = BCH * KIH;            // 16384 u16 (32KB)
constexpr int XELH = BPH * KIH;            // 4096 u16 (8KB)
constexpr int BUFH = CELH + XELH;          // 20480 u16 (40KB)

__global__ __launch_bounds__(512, 2) void argmin_hi_kernel(
    const u16* __restrict__ CBH, const u16* __restrict__ XH,
    const float* __restrict__ cnorm,
    float* __restrict__ pb1h, float* __restrict__ pb2h, int* __restrict__ pi1h)
{
    __shared__ __align__(16) u16 lds[2][BUFH];   // 80 KB

    const int b    = blockIdx.x;
    const int kq   = (b & 7) >> 1;               // K quarter (XCD-affine)
    const int n0   = ((b >> 3) * 2 + (b & 1)) * BPH;
    const int tid  = threadIdx.x;
    const int w    = tid >> 6;
    const int lane = tid & 63;
    const int lhi  = lane >> 4;

    u32 cbo[4], xo;
#pragma unroll
    for (int m = 0; m < 4; ++m) {
        const int flat = m * 512 + tid;
        cbo[m] = (u32)(kq * 1048576 + (flat >> 6) * 8192 + (flat & 63) * 8);
    }
    xo = (u32)((n0 / 16 + (tid >> 6)) * 8192 + (tid & 63) * 8);

    auto stage = [&](int parity) {
        u16* bufp = &lds[parity][0];
#pragma unroll
        for (int m = 0; m < 4; ++m) {
            __builtin_amdgcn_global_load_lds((const AS1 u32*)(CBH + cbo[m]),
                (AS3 u32*)(bufp + (m * 512 + tid) * 8), 16, 0, 0);
            cbo[m] += 512;
        }
        __builtin_amdgcn_global_load_lds((const AS1 u32*)(XH + xo),
            (AS3 u32*)(bufp + CELH + tid * 8), 16, 0, 0);
        xo += 512;
    };

    float b1[8], b2[8]; int i1[8];
#pragma unroll
    for (int p = 0; p < 8; ++p) { b1[p] = INFINITY; b2[p] = INFINITY; i1[p] = 0; }

    stage(0);
    __syncthreads();
    int sc = 1;

    for (int cc = 0; cc < NCHQ; ++cc) {
        f32x4 acc[4][8];
        const f32x4 zero = {0.f, 0.f, 0.f, 0.f};
#pragma unroll
        for (int cg = 0; cg < 4; ++cg)
#pragma unroll
            for (int p = 0; p < 8; ++p) acc[cg][p] = zero;

        for (int s8 = 0; s8 < NSTEPH; ++s8) {
            const u16* cur = &lds[s8 & 1][0];
            if (sc < TOTQ) {
                if ((sc & (NSTEPH - 1)) == 0) {
#pragma unroll
                    for (int m = 0; m < 4; ++m) cbo[m] += 262144 - 8192;
                    xo -= 8192;
                }
                stage(sc & 1);
                ++sc;
            }
            u32x4 bfr[8];
#pragma unroll
            for (int p = 0; p < 8; ++p)
                bfr[p] = *(const u32x4*)(cur + CELH + p * 512 + lane * 8);
#pragma unroll
            for (int cg = 0; cg < 4; ++cg) {
                const u32x4 af = *(const u32x4*)(cur + (w * 4 + cg) * 512 + lane * 8);
#pragma unroll
                for (int p = 0; p < 8; ++p)
                    acc[cg][p] = __builtin_amdgcn_mfma_f32_16x16x32_bf16(
                        __builtin_bit_cast(bf16x8, af),
                        __builtin_bit_cast(bf16x8, bfr[p]), acc[cg][p], 0, 0, 0);
            }
            __syncthreads();
        }

        const int gchunk = kq * NCHQ + cc;
        const int cb0 = gchunk * BCH + w * 64;
#pragma unroll
        for (int cg = 0; cg < 4; ++cg) {
            const int code0 = cb0 + cg * 16 + lhi * 4;
            const float4 cn4 = *(const float4*)(cnorm + code0);
            const float cn[4] = {cn4.x, cn4.y, cn4.z, cn4.w};
#pragma unroll
            for (int p = 0; p < 8; ++p) {
                const f32x4 A = acc[cg][p];
                const float dv[4] = {cn[0] - 2.f * A.x, cn[1] - 2.f * A.y,
                                     cn[2] - 2.f * A.z, cn[3] - 2.f * A.w};
#pragma unroll
                for (int r = 0; r < 4; ++r) {
                    if (dv[r] < b1[p]) { b2[p] = b1[p]; b1[p] = dv[r]; i1[p] = code0 + r; }
                    else if (dv[r] < b2[p]) { b2[p] = dv[r]; }
                }
            }
        }
    }

#pragma unroll
    for (int p = 0; p < 8; ++p) {
#pragma unroll
        for (int m = 16; m <= 32; m <<= 1) {
            const float ob1 = __shfl_xor(b1[p], m, 64);
            const float ob2 = __shfl_xor(b2[p], m, 64);
            const int   oi1 = __shfl_xor(i1[p], m, 64);
            const float nb2 = fminf(fminf(b2[p], ob2), fmaxf(b1[p], ob1));
            if (ob1 < b1[p] || (ob1 == b1[p] && oi1 < i1[p])) { b1[p] = ob1; i1[p] = oi1; }
            b2[p] = nb2;
        }
    }

    __syncthreads();

    float* mb1 = (float*)&lds[0][0];
    float* mb2 = mb1 + 8 * BPH;
    int*   mi  = (int*)(mb2 + 8 * BPH);
    if (lane < 16) {
#pragma unroll
        for (int p = 0; p < 8; ++p) {
            const int pt = p * 16 + lane;
            mb1[w * BPH + pt] = b1[p];
            mb2[w * BPH + pt] = b2[p];
            mi [w * BPH + pt] = i1[p];
        }
    }
    __syncthreads();
    if (tid < BPH) {
        float fb1 = INFINITY, fb2 = INFINITY; int fi = 0;
        for (int ww = 0; ww < 8; ++ww) {
            const float a1 = mb1[ww * BPH + tid], a2 = mb2[ww * BPH + tid];
            const int   ai = mi[ww * BPH + tid];
            const float nb2 = fminf(fminf(fb2, a2), fmaxf(fb1, a1));
            if (a1 < fb1 || (a1 == fb1 && ai < fi)) { fb1 = a1; fi = ai; }
            fb2 = nb2;
        }
        const int n = n0 + tid;
        pb1h[kq * N + n] = fb1;
        pb2h[kq * N + n] = fb2;
        pi1h[kq * N + n] = fi;
    }
}

// ---------------------------------------------------------------------------
__global__ __launch_bounds__(256) void merge_hi_kernel(
    const float* __restrict__ pb1h, const float* __restrict__ pb2h,
    const int* __restrict__ pi1h,
    int* __restrict__ idx_i, float* __restrict__ idx_f,
    int* __restrict__ flag_cnt, int* __restrict__ flag_list,
    int* __restrict__ flag2_cnt, int* __restrict__ flag2_list)
{
    const int n = blockIdx.x * 256 + threadIdx.x;
    float fb1 = INFINITY, fb2 = INFINITY; int fi = 0x7fffffff;
#pragma unroll
    for (int q = 0; q < 4; ++q) {
        const float a1 = pb1h[q * N + n], a2 = pb2h[q * N + n];
        const int   ai = pi1h[q * N + n];
        const float nb2 = fminf(fminf(fb2, a2), fmaxf(fb1, a1));
        if (a1 < fb1 || (a1 == fb1 && ai < fi)) { fb1 = a1; fi = ai; }
        fb2 = nb2;
    }
    idx_i[n] = fi;
    idx_f[n] = (float)fi;
    if (fb2 - fb1 < TAU1) {
        const int pos = atomicAdd(flag_cnt, 1);
        if (pos < CAP) flag_list[pos] = n;
        else {
            const int p2 = atomicAdd(flag2_cnt, 1);
            if ((unsigned)p2 < (unsigned)N) flag2_list[p2] = n;
        }
    }
}

// ---------------------------------------------------------------------------
// Pass 2: split-precision argmin, ONE 512-code chunk per block.
constexpr int CEL2 = 512 * 32;
constexpr int XEL2 = 128 * 32;
constexpr int BUF2 = CEL2 + XEL2;

__global__ __launch_bounds__(512, 2) void argmin_part_kernel(
    const u16* __restrict__ CB2, const u16* __restrict__ PX2,
    const float* __restrict__ cnorm, const int* __restrict__ flag_cnt,
    float* __restrict__ pb1, float* __restrict__ pb2, int* __restrict__ pi1)
{
    const int q  = blockIdx.x & 15;
    const int sb = blockIdx.x >> 4;
    const int cnt = min(*flag_cnt, CAP);
    if (sb * 128 >= cnt) return;
    const int n0s = sb * 128;

    __shared__ __align__(16) u16 lds[2][BUF2];

    const int tid  = threadIdx.x;
    const int w    = tid >> 6;
    const int lane = tid & 63;
    const int lhi  = lane >> 4;

    auto stage = [&](u16* bufp, int s) {
#pragma unroll
        for (int j = 0; j < 4; ++j) {
            const int slot = j * 512 + tid;
            const u16* gsrc = CB2 + (((size_t)(q * 32 + (slot >> 6)) * 32 + s) * 512
                                     + (slot & 63) * 8);
            __builtin_amdgcn_global_load_lds((const AS1 u32*)gsrc,
                                             (AS3 u32*)(bufp + slot * 8), 16, 0, 0);
        }
        const u16* gx = PX2 + (((size_t)(n0s / 16 + (tid >> 6)) * 32 + s) * 512
                               + (tid & 63) * 8);
        __builtin_amdgcn_global_load_lds((const AS1 u32*)gx,
                                         (AS3 u32*)(bufp + CEL2 + tid * 8), 16, 0, 0);
    };

    float b1[8], b2[8]; int i1[8];
#pragma unroll
    for (int p = 0; p < 8; ++p) { b1[p] = INFINITY; b2[p] = INFINITY; i1[p] = 0; }

    f32x4 acc[4][8];
    const f32x4 zero = {0.f, 0.f, 0.f, 0.f};
#pragma unroll
    for (int cg = 0; cg < 4; ++cg)
#pragma unroll
        for (int p = 0; p < 8; ++p) acc[cg][p] = zero;

    stage(&lds[0][0], 0);
    __syncthreads();

#pragma unroll 2
    for (int s = 0; s < 32; ++s) {
        const u16* cur = (s & 1) ? &lds[1][0] : &lds[0][0];
        u16* nxt       = (s & 1) ? &lds[0][0] : &lds[1][0];
        if (s + 1 < 32) stage(nxt, s + 1);

        u32x4 bfr[8];
#pragma unroll
        for (int p = 0; p < 8; ++p)
            bfr[p] = *(const u32x4*)(cur + CEL2 + p * 512 + lane * 8);
#pragma unroll
        for (int cg = 0; cg < 4; ++cg) {
            const u32x4 af = *(const u32x4*)(cur + (w * 4 + cg) * 512 + lane * 8);
            u32x4 as;
            as.x = (af.x >> 16) | (af.x << 16);
            as.y = (af.y >> 16) | (af.y << 16);
            as.z = (af.z >> 16) | (af.z << 16);
            as.w = (af.w >> 16) | (af.w << 16);
#pragma unroll
            for (int p = 0; p < 8; ++p) {
                acc[cg][p] = __builtin_amdgcn_mfma_f32_16x16x32_bf16(
                    __builtin_bit_cast(bf16x8, af), __builtin_bit_cast(bf16x8, bfr[p]),
                    acc[cg][p], 0, 0, 0);
                acc[cg][p] = __builtin_amdgcn_mfma_f32_16x16x32_bf16(
                    __builtin_bit_cast(bf16x8, as), __builtin_bit_cast(bf16x8, bfr[p]),
                    acc[cg][p], 0, 0, 0);
            }
        }
        __syncthreads();
    }

    const int cb0 = q * 512 + w * 64;
#pragma unroll
    for (int cg = 0; cg < 4; ++cg) {
        const int code0 = cb0 + cg * 16 + lhi * 4;
        const float4 cn4 = *(const float4*)(cnorm + code0);
        const float cn[4] = {cn4.x, cn4.y, cn4.z, cn4.w};
#pragma unroll
        for (int p = 0; p < 8; ++p) {
            const f32x4 A = acc[cg][p];
            const float dv[4] = {cn[0] - 2.f * A.x, cn[1] - 2.f * A.y,
                                 cn[2] - 2.f * A.z, cn[3] - 2.f * A.w};
#pragma unroll
            for (int r = 0; r < 4; ++r) {
                if (dv[r] < b1[p]) { b2[p] = b1[p]; b1[p] = dv[r]; i1[p] = code0 + r; }
                else if (dv[r] < b2[p]) { b2[p] = dv[r]; }
            }
        }
    }

#pragma unroll
    for (int p = 0; p < 8; ++p) {
#pragma unroll
        for (int m = 16; m <= 32; m <<= 1) {
            const float ob1 = __shfl_xor(b1[p], m, 64);
            const float ob2 = __shfl_xor(b2[p], m, 64);
            const int   oi1 = __shfl_xor(i1[p], m, 64);
            const float nb2 = fminf(fminf(b2[p], ob2), fmaxf(b1[p], ob1));
            if (ob1 < b1[p] || (ob1 == b1[p] && oi1 < i1[p])) { b1[p] = ob1; i1[p] = oi1; }
            b2[p] = nb2;
        }
    }

    __syncthreads();

    float* mb1 = (float*)&lds[0][0];
    float* mb2 = mb1 + 8 * 128;
    int*   mi  = (int*)(mb2 + 8 * 128);
    if (lane < 16) {
#pragma unroll
        for (int p = 0; p < 8; ++p) {
            const int pt = p * 16 + lane;
            mb1[w * 128 + pt] = b1[p];
            mb2[w * 128 + pt] = b2[p];
            mi [w * 128 + pt] = i1[p];
        }
    }
    __syncthreads();
    if (tid < 128) {
        float fb1 = INFINITY, fb2 = INFINITY; int fi = 0;
        for (int ww = 0; ww < 8; ++ww) {
            const float a1 = mb1[ww * 128 + tid], a2 = mb2[ww * 128 + tid];
            const int   ai = mi[ww * 128 + tid];
            const float nb2 = fminf(fminf(fb2, a2), fmaxf(fb1, a1));
            if (a1 < fb1 || (a1 == fb1 && ai < fi)) { fb1 = a1; fi = ai; }
            fb2 = nb2;
        }
        const int slot = n0s + tid;
        pb1[q * CAP + slot] = fb1;
        pb2[q * CAP + slot] = fb2;
        pi1[q * CAP + slot] = fi;
    }
}

// ---------------------------------------------------------------------------
__global__ __launch_bounds__(256) void combine_kernel(
    const int* __restrict__ flag_cnt, const int* __restrict__ flag_list,
    const float* __restrict__ pb1, const float* __restrict__ pb2,
    const int* __restrict__ pi1,
    int* __restrict__ idx_i, float* __restrict__ idx_f,
    int* __restrict__ flag2_cnt, int* __restrict__ flag2_list)
{
    const int s = blockIdx.x * 256 + threadIdx.x;
    const int cnt = min(*flag_cnt, CAP);
    if (s >= cnt) return;
    float fb1 = INFINITY, fb2 = INFINITY; int fi = 0x7fffffff;
#pragma unroll
    for (int q = 0; q < 16; ++q) {
        const float a1 = pb1[q * CAP + s], a2 = pb2[q * CAP + s];
        const int   ai = pi1[q * CAP + s];
        const float nb2 = fminf(fminf(fb2, a2), fmaxf(fb1, a1));
        if (a1 < fb1 || (a1 == fb1 && ai < fi)) { fb1 = a1; fi = ai; }
        fb2 = nb2;
    }
    const int n = flag_list[s] & (N - 1);
    idx_i[n] = fi;
    idx_f[n] = (float)fi;
    if (fb2 - fb1 < TAU2) {
        const int p2 = atomicAdd(flag2_cnt, 1);
        if ((unsigned)p2 < (unsigned)N) flag2_list[p2] = n;
    }
}

// ---------------------------------------------------------------------------
__global__ __launch_bounds__(256) void exact_part_kernel(
    const float* __restrict__ x, const float* __restrict__ cb,
    const float* __restrict__ cnorm, const int* __restrict__ flag2_cnt,
    const int* __restrict__ flag2_list, u64* __restrict__ eslot)
{
    __shared__ float4 xs[128];
    __shared__ u64 red[256];
    const int cnt = min(*flag2_cnt, CAPE);
    const int nwork = cnt * 16;
    for (int j = blockIdx.x; j < nwork; j += gridDim.x) {
        const int s = j >> 4;
        const int q = j & 15;
        const int n = flag2_list[s] & (N - 1);
        __syncthreads();
        if (threadIdx.x < 128)
            xs[threadIdx.x] = ((const float4*)(x + (size_t)n * D))[threadIdx.x];
        __syncthreads();
        u64 bestp = ~0ull;
#pragma unroll
        for (int c = 0; c < 2; ++c) {
            const int k = q * 512 + c * 256 + threadIdx.x;
            const float4* crow = (const float4*)(cb + (size_t)k * D);
            float a0 = 0.f, a1 = 0.f, a2 = 0.f, a3 = 0.f;
            for (int d = 0; d < 128; ++d) {
                const float4 xv = xs[d], cv = crow[d];
                a0 = fmaf(xv.x, cv.x, a0);
                a1 = fmaf(xv.y, cv.y, a1);
                a2 = fmaf(xv.z, cv.z, a2);
                a3 = fmaf(xv.w, cv.w, a3);
            }
            const float dist = cnorm[k] - 2.0f * ((a0 + a1) + (a2 + a3));
            u32 ub = __builtin_bit_cast(u32, dist);
            ub = (ub & 0x80000000u) ? ~ub : (ub | 0x80000000u);
            const u64 pk = ((u64)ub << 32) | (u32)k;
            bestp = bestp < pk ? bestp : pk;
        }
        red[threadIdx.x] = bestp;
        __syncthreads();
        for (int off = 128; off > 0; off >>= 1) {
            if (threadIdx.x < off) {
                const u64 o = red[threadIdx.x + off];
                if (o < red[threadIdx.x]) red[threadIdx.x] = o;
            }
            __syncthreads();
        }
        if (threadIdx.x == 0) atomicMin(&eslot[s], red[0]);
    }
}

__global__ __launch_bounds__(256) void exact_write_kernel(
    const int* __restrict__ flag2_cnt, const int* __restrict__ flag2_list,
    const u64* __restrict__ eslot, int* __restrict__ idx_i, float* __restrict__ idx_f)
{
    const int s = blockIdx.x * 256 + threadIdx.x;
    const int cnt = min(*flag2_cnt, CAPE);
    if (s >= cnt) return;
    const int n = flag2_list[s] & (N - 1);
    const int k = (int)(eslot[s] & (u64)(K - 1));
    idx_i[n] = k;
    idx_f[n] = (float)k;
}

// ---------------------------------------------------------------------------
__global__ __launch_bounds__(256) void count_kernel(
    const int* __restrict__ idx_i, int* __restrict__ cnti)
{
    const int p = blockIdx.x * 256 + threadIdx.x;
    atomicAdd(&cnti[idx_i[p] & (K - 1)], 1);
}

// ---------------------------------------------------------------------------
__global__ __launch_bounds__(256) void scan_kernel(
    const int* __restrict__ cnti, const float* __restrict__ csz,
    int* __restrict__ offs, int* __restrict__ nxt,
    float* __restrict__ ncs, double* __restrict__ n_sum)
{
    __shared__ int    tsum[256];
    __shared__ double dsum[256];
    const int t = threadIdx.x;
    const int base = t * 32;
    int s = 0;
    double dn = 0.0;
#pragma unroll
    for (int i = 0; i < 32; ++i) {
        const int c = cnti[base + i];
        s += c;
        const float v = DECAYF * csz[base + i] + OMDECAY * (float)c;
        ncs[base + i] = v;
        dn += (double)v;
    }
    tsum[t] = s; dsum[t] = dn;
    __syncthreads();
    int run = 0;
    for (int j = 0; j < t; ++j) run += tsum[j];
#pragma unroll
    for (int i = 0; i < 32; ++i) {
        offs[base + i] = run;
        nxt[base + i] = run;
        run += cnti[base + i];
    }
    if (t == 255) offs[K] = run;
    if (t == 0) {
        double tot = 0.0;
        for (int j = 0; j < 256; ++j) tot += dsum[j];
        n_sum[0] = tot;
    }
}

// ---------------------------------------------------------------------------
__global__ __launch_bounds__(256) void fill_kernel(
    const int* __restrict__ idx_i, int* __restrict__ nxt, int* __restrict__ list)
{
    const int p = blockIdx.x * 256 + threadIdx.x;
    const int k = idx_i[p] & (K - 1);
    const int pos = atomicAdd(&nxt[k], 1);
    if ((unsigned)pos < (unsigned)N) list[pos] = p;
}

// ---------------------------------------------------------------------------
__global__ __launch_bounds__(128) void gather_finalize_kernel(
    const float* __restrict__ x, const float* __restrict__ cb,
    const int* __restrict__ offs, const int* __restrict__ list,
    const float* __restrict__ ema_w, const float* __restrict__ ncs,
    const double* __restrict__ n_sum, float* __restrict__ new_ema,
    float* __restrict__ new_cb, float* __restrict__ zq,
    double* __restrict__ loss_part)
{
    const int k = blockIdx.x;
    const int t = threadIdx.x;
    const int beg = min(offs[k], N), end = min(offs[k + 1], N);
    const size_t o = (size_t)k * 128 + t;
    const float4 c = ((const float4*)cb)[o];
    float4 acc = {0.f, 0.f, 0.f, 0.f};
    float lsum = 0.f;
    for (int i = beg; i < end; ++i) {
        const int p = list[i] & (N - 1);
        const float4 v = ((const float4*)x)[(size_t)p * 128 + t];
        acc.x += v.x; acc.y += v.y; acc.z += v.z; acc.w += v.w;
        ((float4*)zq)[(size_t)p * 128 + t] = c;
        const float d0 = v.x - c.x, d1 = v.y - c.y, d2 = v.z - c.z, d3 = v.w - c.w;
        lsum += d0 * d0 + d1 * d1 + d2 * d2 + d3 * d3;
    }
    const float n = (float)n_sum[0];
    const float csm = (ncs[k] + EPSF) / (n + KEPSF) * n;
    const float4 e = ((const float4*)ema_w)[o];
    float4 ne;
    ne.x = DECAYF * e.x + OMDECAY * acc.x;
    ne.y = DECAYF * e.y + OMDECAY * acc.y;
    ne.z = DECAYF * e.z + OMDECAY * acc.z;
    ne.w = DECAYF * e.w + OMDECAY * acc.w;
    ((float4*)new_ema)[o] = ne;
    float4 nc;
    nc.x = ne.x / csm; nc.y = ne.y / csm; nc.z = ne.z / csm; nc.w = ne.w / csm;
    ((float4*)new_cb)[o] = nc;

#pragma unroll
    for (int m = 32; m >= 1; m >>= 1) lsum += __shfl_xor(lsum, m, 64);
    __shared__ float prt[2];
    if ((t & 63) == 0) prt[t >> 6] = lsum;
    __syncthreads();
    if (t == 0) loss_part[k] = (double)(prt[0] + prt[1]);
}

// ---------------------------------------------------------------------------
__global__ __launch_bounds__(256) void loss_reduce_kernel(
    const double* __restrict__ loss_part, float* __restrict__ out_loss)
{
    __shared__ double red[256];
    const int t = threadIdx.x;
    double s = 0.0;
    for (int i = t; i < K; i += 256) s += loss_part[i];
    red[t] = s;
    __syncthreads();
    for (int off = 128; off > 0; off >>= 1) {
        if (t < off) red[t] += red[t + off];
        __syncthreads();
    }
    if (t == 0)
        out_loss[0] = (float)(1.25 * (red[0] / (double)((size_t)N * D)));
}

// ---------------------------------------------------------------------------
extern "C" void kernel_launch(void* const* d_in, const int* in_sizes, int n_in,
                              void* d_out, int out_size, void* d_ws, size_t ws_size,
                              hipStream_t stream)
{
    const float* z_e   = (const float*)d_in[0];
    const float* cbook = (const float*)d_in[1];
    const float* csz   = (const float*)d_in[2];
    const float* ema_w = (const float*)d_in[3];

    float* out = (float*)d_out;
    u32*   ws  = (u32*)d_ws;

    float*  cnorm      = (float*)(ws + OFF_CNORM);
    int*    idx_i      = (int*)(ws + OFF_IDX);
    int*    cnti       = (int*)(ws + OFF_CNTI);
    int*    flag_cnt   = (int*)(ws + OFF_FLAGC);
    int*    flag2_cnt  = (int*)(ws + OFF_FLAG2C);
    int*    nxt        = (int*)(ws + OFF_NEXT);
    int*    offs       = (int*)(ws + OFF_OFFS);
    int*    list       = (int*)(ws + OFF_LIST);
    int*    flag_list  = (int*)(ws + OFF_FLAGL);
    int*    flag2_list = (int*)(ws + OFF_FLAG2L);
    float*  pb1        = (float*)(ws + OFF_PB1);
    float*  pb2        = (float*)(ws + OFF_PB2);
    int*    pi1        = (int*)(ws + OFF_PI1);
    u64*    eslot      = (u64*)(ws + OFF_ESLOT);
    double* n_sum      = (double*)(ws + OFF_SUMS);
    double* loss_part  = (double*)(ws + OFF_LOSSP);
    u16*    CBH        = (u16*)(ws + OFF_CBH);

    u16* XH  = (u16*)(out + XH_F);
    u16* PX2 = (u16*)(out + PX2_F);
    u16* CB2 = (u16*)(out + OUT_NCB);
    float* pb1h = out + PB1H_F;
    float* pb2h = out + PB2H_F;
    int*   pi1h = (int*)(out + PI1H_F);

    hipMemsetAsync(ws + OFF_CNTI, 0, (K + 2) * sizeof(u32), stream);
    hipMemsetAsync(ws + OFF_ESLOT, 0xFF, CAPE * sizeof(u64), stream);

    split_hi_kernel<<<N / 16, 256, 0, stream>>>(z_e, (u32x4*)XH);
    cbprep_kernel<<<K / 16, 256, 0, stream>>>(cbook, (u32x4*)CBH, (u32x4*)CB2, cnorm);

    argmin_hi_kernel<<<(N / BPH) * 4, 512, 0, stream>>>(CBH, XH, cnorm,
                                                        pb1h, pb2h, pi1h);

    merge_hi_kernel<<<N / 256, 256, 0, stream>>>(pb1h, pb2h, pi1h, idx_i,
                                                 out + OUT_IDX, flag_cnt, flag_list,
                                                 flag2_cnt, flag2_list);

    repack_kernel<<<CAP / 16, 256, 0, stream>>>(z_e, flag_cnt, flag_list, (u32x4*)PX2);

    argmin_part_kernel<<<(CAP / 128) * 16, 512, 0, stream>>>(CB2, PX2, cnorm, flag_cnt,
                                                             pb1, pb2, pi1);

    combine_kernel<<<CAP / 256, 256, 0, stream>>>(flag_cnt, flag_list, pb1, pb2, pi1,
                                                  idx_i, out + OUT_IDX,
                                                  flag2_cnt, flag2_list);

    exact_part_kernel<<<2048, 256, 0, stream>>>(z_e, cbook, cnorm, flag2_cnt,
                                                flag2_list, eslot);

    exact_write_kernel<<<CAPE / 256, 256, 0, stream>>>(flag2_cnt, flag2_list, eslot,
                                                       idx_i, out + OUT_IDX);

    count_kernel<<<N / 256, 256, 0, stream>>>(idx_i, cnti);

    scan_kernel<<<1, 256, 0, stream>>>(cnti, csz, offs, nxt, out + OUT_NCS, n_sum);

    fill_kernel<<<N / 256, 256, 0, stream>>>(idx_i, nxt, list);

    gather_finalize_kernel<<<K, 128, 0, stream>>>(z_e, cbook, offs, list, ema_w,
                                                  out + OUT_NCS, n_sum,
                                                  out + OUT_EMA, out + OUT_NCB,
                                                  out + OUT_ZQ, loss_part);

    loss_reduce_kernel<<<1, 256, 0, stream>>>(loss_part, out + OUT_LOSS);
}

// Round 17
// 745.148 us; speedup vs baseline: 1.2070x; 1.0129x over previous
//
#include <hip/hip_runtime.h>

// VQ-VAE EMA vector quantizer, MI355X.
// R17: argmin_hi retiled to the staged-bytes minimum. Model (R10-R16):
// time = staged_bytes / 9.3 B/cyc/CU with acc-reg cap BP*BC<=65536.
// BP=128,BC=512 -> 2.6GB (456us measured). Symmetric BP=256,BC=256 -> 2.1GB
// (predicted ~390us). 8 waves = 2 point-halves x 4 code-quarters; 64KB LDS.
// All other kernels = R16 (TAU1=0.7, TAU2=0.005, fused cbprep).

constexpr int N = 32768;   // B*L
constexpr int D = 512;
constexpr int K = 8192;
constexpr int CAP  = 8192;
constexpr int CAPE = 4096;

constexpr float DECAYF  = 0.99f;
constexpr float OMDECAY = (float)(1.0 - 0.99);
constexpr float EPSF    = 1e-6f;
constexpr float KEPSF   = (float)(8192 * 1e-6);
constexpr float TAU1    = 0.7f;
constexpr float TAU2    = 0.005f;

typedef unsigned int       u32;
typedef unsigned short     u16;
typedef unsigned long long u64;
typedef float  f32x4 __attribute__((ext_vector_type(4)));
typedef u32    u32x4 __attribute__((ext_vector_type(4)));
typedef __bf16 bf16x8 __attribute__((ext_vector_type(8)));

#define AS1 __attribute__((address_space(1)))
#define AS3 __attribute__((address_space(3)))

// ---- workspace layout (32-bit word offsets) ----
constexpr size_t OFF_CNORM  = 0;
constexpr size_t OFF_IDX    = OFF_CNORM + K;
constexpr size_t OFF_CNTI   = OFF_IDX + N;
constexpr size_t OFF_FLAGC  = OFF_CNTI + K;
constexpr size_t OFF_FLAG2C = OFF_FLAGC + 1;
constexpr size_t OFF_NEXT   = OFF_FLAG2C + 1;
constexpr size_t OFF_OFFS   = OFF_NEXT + K;
constexpr size_t OFF_LIST   = OFF_OFFS + K + 1;
constexpr size_t OFF_FLAGL  = OFF_LIST + N;
constexpr size_t OFF_FLAG2L = OFF_FLAGL + CAP;
constexpr size_t OFF_PB1    = OFF_FLAG2L + N;
constexpr size_t OFF_PB2    = OFF_PB1 + 16 * CAP;
constexpr size_t OFF_PI1    = OFF_PB2 + 16 * CAP;
constexpr size_t OFF_ESLOT  = (OFF_PI1 + 16 * CAP + 1) & ~(size_t)1;
constexpr size_t OFF_SUMS   = (OFF_ESLOT + 2 * CAPE + 1) & ~(size_t)1;
constexpr size_t OFF_LOSSP  = (OFF_SUMS + 2 + 1) & ~(size_t)1;
constexpr size_t OFF_CBH    = (OFF_LOSSP + 2 * K + 3) & ~(size_t)3;
static_assert((OFF_ESLOT & 1) == 0 && (OFF_SUMS & 1) == 0 && (OFF_LOSSP & 1) == 0, "align");
static_assert((OFF_CBH & 3) == 0, "16B align");

// ---- output layout (float offsets) ----
constexpr size_t OUT_ZQ   = 0;
constexpr size_t OUT_IDX  = OUT_ZQ + (size_t)N * D;
constexpr size_t OUT_LOSS = OUT_IDX + N;
constexpr size_t OUT_NCB  = OUT_LOSS + 1;
constexpr size_t OUT_NCS  = OUT_NCB + (size_t)K * D;
constexpr size_t OUT_EMA  = OUT_NCS + K;
constexpr size_t XH_F  = OUT_ZQ;
constexpr size_t PX2_F = OUT_ZQ + (size_t)N * 256;
constexpr size_t PB1H_F = OUT_EMA;
constexpr size_t PB2H_F = OUT_EMA + 4 * (size_t)N;
constexpr size_t PI1H_F = OUT_EMA + 8 * (size_t)N;

// ---------------------------------------------------------------------------
__device__ inline u16 f32_to_bf16_rne(float f)
{
    u32 u = __builtin_bit_cast(u32, f);
    u = (u + 0x7FFFu + ((u >> 16) & 1u)) >> 16;
    return (u16)u;
}

// hi-only split of z_e: [rows/16][16 slices][64 lanes][8 u16]
__global__ __launch_bounds__(256) void split_hi_kernel(const float* __restrict__ src,
                                                       u32x4* __restrict__ dst)
{
    const int T = blockIdx.x;
    const int w = threadIdx.x >> 6;
    const int l = threadIdx.x & 63;
    const int row = T * 16 + (l & 15);
#pragma unroll
    for (int i = 0; i < 4; ++i) {
        const int S  = w * 4 + i;
        const int q4 = S * 8 + (l >> 4) * 2;
        const float4 va = ((const float4*)src)[(size_t)row * 128 + q4];
        const float4 vb = ((const float4*)src)[(size_t)row * 128 + q4 + 1];
        const float a[8] = {va.x, va.y, va.z, va.w, vb.x, vb.y, vb.z, vb.w};
        u32x4 o;
#pragma unroll
        for (int j = 0; j < 4; ++j)
            ((u32*)&o)[j] = (u32)f32_to_bf16_rne(a[2 * j]) |
                            ((u32)f32_to_bf16_rne(a[2 * j + 1]) << 16);
        dst[((size_t)T * 16 + S) * 64 + l] = o;
    }
}

// fused codebook prep: hi-split -> CBH, interleaved split -> CB2, norms -> cnorm
__global__ __launch_bounds__(256) void cbprep_kernel(const float* __restrict__ cb,
                                                     u32x4* __restrict__ CBH,
                                                     u32x4* __restrict__ CB2,
                                                     float* __restrict__ cnorm)
{
    const int T = blockIdx.x;
    const int w = threadIdx.x >> 6;
    const int l = threadIdx.x & 63;
    {
        const int row = T * 16 + (l & 15);
#pragma unroll
        for (int i = 0; i < 4; ++i) {
            const int S  = w * 4 + i;
            const int q4 = S * 8 + (l >> 4) * 2;
            const float4 va = ((const float4*)cb)[(size_t)row * 128 + q4];
            const float4 vb = ((const float4*)cb)[(size_t)row * 128 + q4 + 1];
            const float a[8] = {va.x, va.y, va.z, va.w, vb.x, vb.y, vb.z, vb.w};
            u32x4 o;
#pragma unroll
            for (int j = 0; j < 4; ++j)
                ((u32*)&o)[j] = (u32)f32_to_bf16_rne(a[2 * j]) |
                                ((u32)f32_to_bf16_rne(a[2 * j + 1]) << 16);
            CBH[((size_t)T * 16 + S) * 64 + l] = o;
        }
    }
    {
        const int row = T * 16 + (l & 15);
        const int cq  = l >> 4;
#pragma unroll
        for (int i = 0; i < 8; ++i) {
            const int S = w + 4 * i;
            const float4 v = ((const float4*)cb)[(size_t)row * 128 + S * 4 + cq];
            u32x4 o;
            const float a[4] = {v.x, v.y, v.z, v.w};
#pragma unroll
            for (int j = 0; j < 4; ++j) {
                const u16 hi = f32_to_bf16_rne(a[j]);
                const float hif = __builtin_bit_cast(float, (u32)hi << 16);
                const u16 lo = f32_to_bf16_rne(a[j] - hif);
                ((u32*)&o)[j] = (u32)hi | ((u32)lo << 16);
            }
            CB2[((size_t)T * 32 + S) * 64 + l] = o;
        }
    }
#pragma unroll
    for (int sub = 0; sub < 4; ++sub) {
        const int row = T * 16 + sub * 4 + w;
        const float4* r = (const float4*)(cb + (size_t)row * D);
        const float4 v0 = r[l];
        const float4 v1 = r[l + 64];
        float s = v0.x * v0.x + v0.y * v0.y + v0.z * v0.z + v0.w * v0.w
                + v1.x * v1.x + v1.y * v1.y + v1.z * v1.z + v1.w * v1.w;
#pragma unroll
        for (int m = 32; m >= 1; m >>= 1) s += __shfl_xor(s, m, 64);
        if (l == 0) cnorm[row] = s;
    }
}

// indirect split of flagged points -> PX2 interleaved frag order
__global__ __launch_bounds__(256) void repack_kernel(
    const float* __restrict__ z_e, const int* __restrict__ flag_cnt,
    const int* __restrict__ flag_list, u32x4* __restrict__ PX2)
{
    const int B = blockIdx.x;
    const int cnt = min(*flag_cnt, CAP);
    if (B * 16 >= cnt) return;
    const int w = threadIdx.x >> 6;
    const int l = threadIdx.x & 63;
    const int srow = B * 16 + (l & 15);
    const int n = (srow < cnt) ? (flag_list[srow] & (N - 1)) : 0;
    const int cq = l >> 4;
#pragma unroll
    for (int i = 0; i < 8; ++i) {
        const int S = w + 4 * i;
        const float4 v = ((const float4*)z_e)[(size_t)n * 128 + S * 4 + cq];
        u32x4 o;
        const float a[4] = {v.x, v.y, v.z, v.w};
#pragma unroll
        for (int j = 0; j < 4; ++j) {
            const u16 hi = f32_to_bf16_rne(a[j]);
            const float hif = __builtin_bit_cast(float, (u32)hi << 16);
            const u16 lo = f32_to_bf16_rne(a[j] - hif);
            ((u32*)&o)[j] = (u32)hi | ((u32)lo << 16);
        }
        PX2[((size_t)B * 32 + S) * 64 + l] = o;
    }
}

// ---------------------------------------------------------------------------
// Pass 1: hi-only argmin, symmetric tile BP=256 x BC=256 (staged-bytes min).
// 512 thr = 8 waves: wave w = (wp = w>>2 point-half, wc = w&3 code-quarter).
// K-quarter split (8 chunks of 256 codes), KI=32, 2x32KB LDS dbuf.
constexpr int BPH = 256, BCH = 256, KIH = 32;
constexpr int NSTEPH = 16;                 // slices per chunk
constexpr int NCHQ   = 8;                  // chunks per quarter (2048/256)
constexpr int TOTQ   = NCHQ * NSTEPH;      // 128 steps/block
constexpr int CELH = BCH * KIH;            // 8192 u16 (16KB)
constexpr int XELH = BPH * KIH;            // 8192 u16 (16KB)
constexpr int BUFH = CELH + XELH;          // 16384 u16 (32KB)

__global__ __launch_bounds__(512, 2) void argmin_hi_kernel(
    const u16* __restrict__ CBH, const u16* __restrict__ XH,
    const float* __restrict__ cnorm,
    float* __restrict__ pb1h, float* __restrict__ pb2h, int* __restrict__ pi1h)
{
    __shared__ __align__(16) u16 lds[2][BUFH];   // 64 KB

    const int b    = blockIdx.x;
    const int kq   = (b & 7) >> 1;               // K quarter (XCD-affine)
    const int n0   = ((b >> 3) * 2 + (b & 1)) * BPH;
    const int tid  = threadIdx.x;
    const int w    = tid >> 6;
    const int wp   = w >> 2;                     // point half (0,1)
    const int wc   = w & 3;                      // code quarter-of-chunk (0..3)
    const int lane = tid & 63;
    const int lhi  = lane >> 4;

    // incremental u16 offsets; layouts [groups][16 slices][64 lanes][8]:
    // group stride 8192, slice stride 512.
    u32 cbo[2], xo[2];
#pragma unroll
    for (int m = 0; m < 2; ++m) {
        const int flat = m * 512 + tid;          // [0,1024): 16 groups x 64 lanes
        const int g = flat >> 6, li = flat & 63;
        cbo[m] = (u32)((kq * 128 + g) * 8192 + li * 8);
        xo[m]  = (u32)((n0 / 16 + g) * 8192 + li * 8);
    }

    auto stage = [&](int parity) {
        u16* bufp = &lds[parity][0];
#pragma unroll
        for (int m = 0; m < 2; ++m) {
            __builtin_amdgcn_global_load_lds((const AS1 u32*)(CBH + cbo[m]),
                (AS3 u32*)(bufp + (m * 512 + tid) * 8), 16, 0, 0);
            cbo[m] += 512;
            __builtin_amdgcn_global_load_lds((const AS1 u32*)(XH + xo[m]),
                (AS3 u32*)(bufp + CELH + (m * 512 + tid) * 8), 16, 0, 0);
            xo[m] += 512;
        }
    };

    float b1[8], b2[8]; int i1[8];
#pragma unroll
    for (int p = 0; p < 8; ++p) { b1[p] = INFINITY; b2[p] = INFINITY; i1[p] = 0; }

    stage(0);
    __syncthreads();
    int sc = 1;

    for (int cc = 0; cc < NCHQ; ++cc) {
        f32x4 acc[4][8];
        const f32x4 zero = {0.f, 0.f, 0.f, 0.f};
#pragma unroll
        for (int cg = 0; cg < 4; ++cg)
#pragma unroll
            for (int p = 0; p < 8; ++p) acc[cg][p] = zero;

        for (int s8 = 0; s8 < NSTEPH; ++s8) {
            const u16* cur = &lds[s8 & 1][0];
            if (sc < TOTQ) {
                if ((sc & (NSTEPH - 1)) == 0) {  // chunk crossing
#pragma unroll
                    for (int m = 0; m < 2; ++m) {
                        cbo[m] += 16 * 8192 - 8192;  // next 16 cb groups, rewind s
                        xo[m]  -= 8192;              // rewind s (same points)
                    }
                }
                stage(sc & 1);
                ++sc;
            }
            u32x4 bfr[8];
#pragma unroll
            for (int p = 0; p < 8; ++p)
                bfr[p] = *(const u32x4*)(cur + CELH + (wp * 8 + p) * 512 + lane * 8);
#pragma unroll
            for (int cg = 0; cg < 4; ++cg) {
                const u32x4 af = *(const u32x4*)(cur + (wc * 4 + cg) * 512 + lane * 8);
#pragma unroll
                for (int p = 0; p < 8; ++p)
                    acc[cg][p] = __builtin_amdgcn_mfma_f32_16x16x32_bf16(
                        __builtin_bit_cast(bf16x8, af),
                        __builtin_bit_cast(bf16x8, bfr[p]), acc[cg][p], 0, 0, 0);
            }
            __syncthreads();
        }

        // epilogue: codes ascending within chunk (cg ascending under fixed wc)
        const int cb0 = kq * 2048 + cc * 256 + wc * 64;
#pragma unroll
        for (int cg = 0; cg < 4; ++cg) {
            const int code0 = cb0 + cg * 16 + lhi * 4;
            const float4 cn4 = *(const float4*)(cnorm + code0);
            const float cn[4] = {cn4.x, cn4.y, cn4.z, cn4.w};
#pragma unroll
            for (int p = 0; p < 8; ++p) {
                const f32x4 A = acc[cg][p];
                const float dv[4] = {cn[0] - 2.f * A.x, cn[1] - 2.f * A.y,
                                     cn[2] - 2.f * A.z, cn[3] - 2.f * A.w};
#pragma unroll
                for (int r = 0; r < 4; ++r) {
                    if (dv[r] < b1[p]) { b2[p] = b1[p]; b1[p] = dv[r]; i1[p] = code0 + r; }
                    else if (dv[r] < b2[p]) { b2[p] = dv[r]; }
                }
            }
        }
    }

    // cross-lane merge (lanes {x, x+16, x+32, x+48} hold same point)
#pragma unroll
    for (int p = 0; p < 8; ++p) {
#pragma unroll
        for (int m = 16; m <= 32; m <<= 1) {
            const float ob1 = __shfl_xor(b1[p], m, 64);
            const float ob2 = __shfl_xor(b2[p], m, 64);
            const int   oi1 = __shfl_xor(i1[p], m, 64);
            const float nb2 = fminf(fminf(b2[p], ob2), fmaxf(b1[p], ob1));
            if (ob1 < b1[p] || (ob1 == b1[p] && oi1 < i1[p])) { b1[p] = ob1; i1[p] = oi1; }
            b2[p] = nb2;
        }
    }

    __syncthreads();   // drain before LDS reuse

    // per-wave partials: wave w covers points [wp*128, wp*128+128)
    float* mb1 = (float*)&lds[0][0];
    float* mb2 = mb1 + 8 * 128;
    int*   mi  = (int*)(mb2 + 8 * 128);
    if (lane < 16) {
#pragma unroll
        for (int p = 0; p < 8; ++p) {
            const int pt = p * 16 + lane;         // point within half
            mb1[w * 128 + pt] = b1[p];
            mb2[w * 128 + pt] = b2[p];
            mi [w * 128 + pt] = i1[p];
        }
    }
    __syncthreads();
    if (tid < BPH) {                              // 256 threads, one per point
        const int wp2 = tid >> 7;
        const int pt  = tid & 127;
        float fb1 = INFINITY, fb2 = INFINITY; int fi = 0;
        for (int ww = 0; ww < 4; ++ww) {          // ascending wc = ascending codes
            const int src = (wp2 * 4 + ww) * 128 + pt;
            const float a1 = mb1[src], a2 = mb2[src];
            const int   ai = mi[src];
            const float nb2 = fminf(fminf(fb2, a2), fmaxf(fb1, a1));
            if (a1 < fb1 || (a1 == fb1 && ai < fi)) { fb1 = a1; fi = ai; }
            fb2 = nb2;
        }
        const int n = n0 + tid;
        pb1h[kq * N + n] = fb1;
        pb2h[kq * N + n] = fb2;
        pi1h[kq * N + n] = fi;
    }
}

// ---------------------------------------------------------------------------
__global__ __launch_bounds__(256) void merge_hi_kernel(
    const float* __restrict__ pb1h, const float* __restrict__ pb2h,
    const int* __restrict__ pi1h,
    int* __restrict__ idx_i, float* __restrict__ idx_f,
    int* __restrict__ flag_cnt, int* __restrict__ flag_list,
    int* __restrict__ flag2_cnt, int* __restrict__ flag2_list)
{
    const int n = blockIdx.x * 256 + threadIdx.x;
    float fb1 = INFINITY, fb2 = INFINITY; int fi = 0x7fffffff;
#pragma unroll
    for (int q = 0; q < 4; ++q) {
        const float a1 = pb1h[q * N + n], a2 = pb2h[q * N + n];
        const int   ai = pi1h[q * N + n];
        const float nb2 = fminf(fminf(fb2, a2), fmaxf(fb1, a1));
        if (a1 < fb1 || (a1 == fb1 && ai < fi)) { fb1 = a1; fi = ai; }
        fb2 = nb2;
    }
    idx_i[n] = fi;
    idx_f[n] = (float)fi;
    if (fb2 - fb1 < TAU1) {
        const int pos = atomicAdd(flag_cnt, 1);
        if (pos < CAP) flag_list[pos] = n;
        else {
            const int p2 = atomicAdd(flag2_cnt, 1);
            if ((unsigned)p2 < (unsigned)N) flag2_list[p2] = n;
        }
    }
}

// ---------------------------------------------------------------------------
// Pass 2: split-precision argmin, ONE 512-code chunk per block.
constexpr int CEL2 = 512 * 32;
constexpr int XEL2 = 128 * 32;
constexpr int BUF2 = CEL2 + XEL2;

__global__ __launch_bounds__(512, 2) void argmin_part_kernel(
    const u16* __restrict__ CB2, const u16* __restrict__ PX2,
    const float* __restrict__ cnorm, const int* __restrict__ flag_cnt,
    float* __restrict__ pb1, float* __restrict__ pb2, int* __restrict__ pi1)
{
    const int q  = blockIdx.x & 15;
    const int sb = blockIdx.x >> 4;
    const int cnt = min(*flag_cnt, CAP);
    if (sb * 128 >= cnt) return;
    const int n0s = sb * 128;

    __shared__ __align__(16) u16 lds[2][BUF2];

    const int tid  = threadIdx.x;
    const int w    = tid >> 6;
    const int lane = tid & 63;
    const int lhi  = lane >> 4;

    auto stage = [&](u16* bufp, int s) {
#pragma unroll
        for (int j = 0; j < 4; ++j) {
            const int slot = j * 512 + tid;
            const u16* gsrc = CB2 + (((size_t)(q * 32 + (slot >> 6)) * 32 + s) * 512
                                     + (slot & 63) * 8);
            __builtin_amdgcn_global_load_lds((const AS1 u32*)gsrc,
                                             (AS3 u32*)(bufp + slot * 8), 16, 0, 0);
        }
        const u16* gx = PX2 + (((size_t)(n0s / 16 + (tid >> 6)) * 32 + s) * 512
                               + (tid & 63) * 8);
        __builtin_amdgcn_global_load_lds((const AS1 u32*)gx,
                                         (AS3 u32*)(bufp + CEL2 + tid * 8), 16, 0, 0);
    };

    float b1[8], b2[8]; int i1[8];
#pragma unroll
    for (int p = 0; p < 8; ++p) { b1[p] = INFINITY; b2[p] = INFINITY; i1[p] = 0; }

    f32x4 acc[4][8];
    const f32x4 zero = {0.f, 0.f, 0.f, 0.f};
#pragma unroll
    for (int cg = 0; cg < 4; ++cg)
#pragma unroll
        for (int p = 0; p < 8; ++p) acc[cg][p] = zero;

    stage(&lds[0][0], 0);
    __syncthreads();

#pragma unroll 2
    for (int s = 0; s < 32; ++s) {
        const u16* cur = (s & 1) ? &lds[1][0] : &lds[0][0];
        u16* nxt       = (s & 1) ? &lds[0][0] : &lds[1][0];
        if (s + 1 < 32) stage(nxt, s + 1);

        u32x4 bfr[8];
#pragma unroll
        for (int p = 0; p < 8; ++p)
            bfr[p] = *(const u32x4*)(cur + CEL2 + p * 512 + lane * 8);
#pragma unroll
        for (int cg = 0; cg < 4; ++cg) {
            const u32x4 af = *(const u32x4*)(cur + (w * 4 + cg) * 512 + lane * 8);
            u32x4 as;
            as.x = (af.x >> 16) | (af.x << 16);
            as.y = (af.y >> 16) | (af.y << 16);
            as.z = (af.z >> 16) | (af.z << 16);
            as.w = (af.w >> 16) | (af.w << 16);
#pragma unroll
            for (int p = 0; p < 8; ++p) {
                acc[cg][p] = __builtin_amdgcn_mfma_f32_16x16x32_bf16(
                    __builtin_bit_cast(bf16x8, af), __builtin_bit_cast(bf16x8, bfr[p]),
                    acc[cg][p], 0, 0, 0);
                acc[cg][p] = __builtin_amdgcn_mfma_f32_16x16x32_bf16(
                    __builtin_bit_cast(bf16x8, as), __builtin_bit_cast(bf16x8, bfr[p]),
                    acc[cg][p], 0, 0, 0);
            }
        }
        __syncthreads();
    }

    const int cb0 = q * 512 + w * 64;
#pragma unroll
    for (int cg = 0; cg < 4; ++cg) {
        const int code0 = cb0 + cg * 16 + lhi * 4;
        const float4 cn4 = *(const float4*)(cnorm + code0);
        const float cn[4] = {cn4.x, cn4.y, cn4.z, cn4.w};
#pragma unroll
        for (int p = 0; p < 8; ++p) {
            const f32x4 A = acc[cg][p];
            const float dv[4] = {cn[0] - 2.f * A.x, cn[1] - 2.f * A.y,
                                 cn[2] - 2.f * A.z, cn[3] - 2.f * A.w};
#pragma unroll
            for (int r = 0; r < 4; ++r) {
                if (dv[r] < b1[p]) { b2[p] = b1[p]; b1[p] = dv[r]; i1[p] = code0 + r; }
                else if (dv[r] < b2[p]) { b2[p] = dv[r]; }
            }
        }
    }

#pragma unroll
    for (int p = 0; p < 8; ++p) {
#pragma unroll
        for (int m = 16; m <= 32; m <<= 1) {
            const float ob1 = __shfl_xor(b1[p], m, 64);
            const float ob2 = __shfl_xor(b2[p], m, 64);
            const int   oi1 = __shfl_xor(i1[p], m, 64);
            const float nb2 = fminf(fminf(b2[p], ob2), fmaxf(b1[p], ob1));
            if (ob1 < b1[p] || (ob1 == b1[p] && oi1 < i1[p])) { b1[p] = ob1; i1[p] = oi1; }
            b2[p] = nb2;
        }
    }

    __syncthreads();

    float* mb1 = (float*)&lds[0][0];
    float* mb2 = mb1 + 8 * 128;
    int*   mi  = (int*)(mb2 + 8 * 128);
    if (lane < 16) {
#pragma unroll
        for (int p = 0; p < 8; ++p) {
            const int pt = p * 16 + lane;
            mb1[w * 128 + pt] = b1[p];
            mb2[w * 128 + pt] = b2[p];
            mi [w * 128 + pt] = i1[p];
        }
    }
    __syncthreads();
    if (tid < 128) {
        float fb1 = INFINITY, fb2 = INFINITY; int fi = 0;
        for (int ww = 0; ww < 8; ++ww) {
            const float a1 = mb1[ww * 128 + tid], a2 = mb2[ww * 128 + tid];
            const int   ai = mi[ww * 128 + tid];
            const float nb2 = fminf(fminf(fb2, a2), fmaxf(fb1, a1));
            if (a1 < fb1 || (a1 == fb1 && ai < fi)) { fb1 = a1; fi = ai; }
            fb2 = nb2;
        }
        const int slot = n0s + tid;
        pb1[q * CAP + slot] = fb1;
        pb2[q * CAP + slot] = fb2;
        pi1[q * CAP + slot] = fi;
    }
}

// ---------------------------------------------------------------------------
__global__ __launch_bounds__(256) void combine_kernel(
    const int* __restrict__ flag_cnt, const int* __restrict__ flag_list,
    const float* __restrict__ pb1, const float* __restrict__ pb2,
    const int* __restrict__ pi1,
    int* __restrict__ idx_i, float* __restrict__ idx_f,
    int* __restrict__ flag2_cnt, int* __restrict__ flag2_list)
{
    const int s = blockIdx.x * 256 + threadIdx.x;
    const int cnt = min(*flag_cnt, CAP);
    if (s >= cnt) return;
    float fb1 = INFINITY, fb2 = INFINITY; int fi = 0x7fffffff;
#pragma unroll
    for (int q = 0; q < 16; ++q) {
        const float a1 = pb1[q * CAP + s], a2 = pb2[q * CAP + s];
        const int   ai = pi1[q * CAP + s];
        const float nb2 = fminf(fminf(fb2, a2), fmaxf(fb1, a1));
        if (a1 < fb1 || (a1 == fb1 && ai < fi)) { fb1 = a1; fi = ai; }
        fb2 = nb2;
    }
    const int n = flag_list[s] & (N - 1);
    idx_i[n] = fi;
    idx_f[n] = (float)fi;
    if (fb2 - fb1 < TAU2) {
        const int p2 = atomicAdd(flag2_cnt, 1);
        if ((unsigned)p2 < (unsigned)N) flag2_list[p2] = n;
    }
}

// ---------------------------------------------------------------------------
__global__ __launch_bounds__(256) void exact_part_kernel(
    const float* __restrict__ x, const float* __restrict__ cb,
    const float* __restrict__ cnorm, const int* __restrict__ flag2_cnt,
    const int* __restrict__ flag2_list, u64* __restrict__ eslot)
{
    __shared__ float4 xs[128];
    __shared__ u64 red[256];
    const int cnt = min(*flag2_cnt, CAPE);
    const int nwork = cnt * 16;
    for (int j = blockIdx.x; j < nwork; j += gridDim.x) {
        const int s = j >> 4;
        const int q = j & 15;
        const int n = flag2_list[s] & (N - 1);
        __syncthreads();
        if (threadIdx.x < 128)
            xs[threadIdx.x] = ((const float4*)(x + (size_t)n * D))[threadIdx.x];
        __syncthreads();
        u64 bestp = ~0ull;
#pragma unroll
        for (int c = 0; c < 2; ++c) {
            const int k = q * 512 + c * 256 + threadIdx.x;
            const float4* crow = (const float4*)(cb + (size_t)k * D);
            float a0 = 0.f, a1 = 0.f, a2 = 0.f, a3 = 0.f;
            for (int d = 0; d < 128; ++d) {
                const float4 xv = xs[d], cv = crow[d];
                a0 = fmaf(xv.x, cv.x, a0);
                a1 = fmaf(xv.y, cv.y, a1);
                a2 = fmaf(xv.z, cv.z, a2);
                a3 = fmaf(xv.w, cv.w, a3);
            }
            const float dist = cnorm[k] - 2.0f * ((a0 + a1) + (a2 + a3));
            u32 ub = __builtin_bit_cast(u32, dist);
            ub = (ub & 0x80000000u) ? ~ub : (ub | 0x80000000u);
            const u64 pk = ((u64)ub << 32) | (u32)k;
            bestp = bestp < pk ? bestp : pk;
        }
        red[threadIdx.x] = bestp;
        __syncthreads();
        for (int off = 128; off > 0; off >>= 1) {
            if (threadIdx.x < off) {
                const u64 o = red[threadIdx.x + off];
                if (o < red[threadIdx.x]) red[threadIdx.x] = o;
            }
            __syncthreads();
        }
        if (threadIdx.x == 0) atomicMin(&eslot[s], red[0]);
    }
}

__global__ __launch_bounds__(256) void exact_write_kernel(
    const int* __restrict__ flag2_cnt, const int* __restrict__ flag2_list,
    const u64* __restrict__ eslot, int* __restrict__ idx_i, float* __restrict__ idx_f)
{
    const int s = blockIdx.x * 256 + threadIdx.x;
    const int cnt = min(*flag2_cnt, CAPE);
    if (s >= cnt) return;
    const int n = flag2_list[s] & (N - 1);
    const int k = (int)(eslot[s] & (u64)(K - 1));
    idx_i[n] = k;
    idx_f[n] = (float)k;
}

// ---------------------------------------------------------------------------
__global__ __launch_bounds__(256) void count_kernel(
    const int* __restrict__ idx_i, int* __restrict__ cnti)
{
    const int p = blockIdx.x * 256 + threadIdx.x;
    atomicAdd(&cnti[idx_i[p] & (K - 1)], 1);
}

// ---------------------------------------------------------------------------
__global__ __launch_bounds__(256) void scan_kernel(
    const int* __restrict__ cnti, const float* __restrict__ csz,
    int* __restrict__ offs, int* __restrict__ nxt,
    float* __restrict__ ncs, double* __restrict__ n_sum)
{
    __shared__ int    tsum[256];
    __shared__ double dsum[256];
    const int t = threadIdx.x;
    const int base = t * 32;
    int s = 0;
    double dn = 0.0;
#pragma unroll
    for (int i = 0; i < 32; ++i) {
        const int c = cnti[base + i];
        s += c;
        const float v = DECAYF * csz[base + i] + OMDECAY * (float)c;
        ncs[base + i] = v;
        dn += (double)v;
    }
    tsum[t] = s; dsum[t] = dn;
    __syncthreads();
    int run = 0;
    for (int j = 0; j < t; ++j) run += tsum[j];
#pragma unroll
    for (int i = 0; i < 32; ++i) {
        offs[base + i] = run;
        nxt[base + i] = run;
        run += cnti[base + i];
    }
    if (t == 255) offs[K] = run;
    if (t == 0) {
        double tot = 0.0;
        for (int j = 0; j < 256; ++j) tot += dsum[j];
        n_sum[0] = tot;
    }
}

// ---------------------------------------------------------------------------
__global__ __launch_bounds__(256) void fill_kernel(
    const int* __restrict__ idx_i, int* __restrict__ nxt, int* __restrict__ list)
{
    const int p = blockIdx.x * 256 + threadIdx.x;
    const int k = idx_i[p] & (K - 1);
    const int pos = atomicAdd(&nxt[k], 1);
    if ((unsigned)pos < (unsigned)N) list[pos] = p;
}

// ---------------------------------------------------------------------------
__global__ __launch_bounds__(128) void gather_finalize_kernel(
    const float* __restrict__ x, const float* __restrict__ cb,
    const int* __restrict__ offs, const int* __restrict__ list,
    const float* __restrict__ ema_w, const float* __restrict__ ncs,
    const double* __restrict__ n_sum, float* __restrict__ new_ema,
    float* __restrict__ new_cb, float* __restrict__ zq,
    double* __restrict__ loss_part)
{
    const int k = blockIdx.x;
    const int t = threadIdx.x;
    const int beg = min(offs[k], N), end = min(offs[k + 1], N);
    const size_t o = (size_t)k * 128 + t;
    const float4 c = ((const float4*)cb)[o];
    float4 acc = {0.f, 0.f, 0.f, 0.f};
    float lsum = 0.f;
    for (int i = beg; i < end; ++i) {
        const int p = list[i] & (N - 1);
        const float4 v = ((const float4*)x)[(size_t)p * 128 + t];
        acc.x += v.x; acc.y += v.y; acc.z += v.z; acc.w += v.w;
        ((float4*)zq)[(size_t)p * 128 + t] = c;
        const float d0 = v.x - c.x, d1 = v.y - c.y, d2 = v.z - c.z, d3 = v.w - c.w;
        lsum += d0 * d0 + d1 * d1 + d2 * d2 + d3 * d3;
    }
    const float n = (float)n_sum[0];
    const float csm = (ncs[k] + EPSF) / (n + KEPSF) * n;
    const float4 e = ((const float4*)ema_w)[o];
    float4 ne;
    ne.x = DECAYF * e.x + OMDECAY * acc.x;
    ne.y = DECAYF * e.y + OMDECAY * acc.y;
    ne.z = DECAYF * e.z + OMDECAY * acc.z;
    ne.w = DECAYF * e.w + OMDECAY * acc.w;
    ((float4*)new_ema)[o] = ne;
    float4 nc;
    nc.x = ne.x / csm; nc.y = ne.y / csm; nc.z = ne.z / csm; nc.w = ne.w / csm;
    ((float4*)new_cb)[o] = nc;

#pragma unroll
    for (int m = 32; m >= 1; m >>= 1) lsum += __shfl_xor(lsum, m, 64);
    __shared__ float prt[2];
    if ((t & 63) == 0) prt[t >> 6] = lsum;
    __syncthreads();
    if (t == 0) loss_part[k] = (double)(prt[0] + prt[1]);
}

// ---------------------------------------------------------------------------
__global__ __launch_bounds__(256) void loss_reduce_kernel(
    const double* __restrict__ loss_part, float* __restrict__ out_loss)
{
    __shared__ double red[256];
    const int t = threadIdx.x;
    double s = 0.0;
    for (int i = t; i < K; i += 256) s += loss_part[i];
    red[t] = s;
    __syncthreads();
    for (int off = 128; off > 0; off >>= 1) {
        if (t < off) red[t] += red[t + off];
        __syncthreads();
    }
    if (t == 0)
        out_loss[0] = (float)(1.25 * (red[0] / (double)((size_t)N * D)));
}

// ---------------------------------------------------------------------------
extern "C" void kernel_launch(void* const* d_in, const int* in_sizes, int n_in,
                              void* d_out, int out_size, void* d_ws, size_t ws_size,
                              hipStream_t stream)
{
    const float* z_e   = (const float*)d_in[0];
    const float* cbook = (const float*)d_in[1];
    const float* csz   = (const float*)d_in[2];
    const float* ema_w = (const float*)d_in[3];

    float* out = (float*)d_out;
    u32*   ws  = (u32*)d_ws;

    float*  cnorm      = (float*)(ws + OFF_CNORM);
    int*    idx_i      = (int*)(ws + OFF_IDX);
    int*    cnti       = (int*)(ws + OFF_CNTI);
    int*    flag_cnt   = (int*)(ws + OFF_FLAGC);
    int*    flag2_cnt  = (int*)(ws + OFF_FLAG2C);
    int*    nxt        = (int*)(ws + OFF_NEXT);
    int*    offs       = (int*)(ws + OFF_OFFS);
    int*    list       = (int*)(ws + OFF_LIST);
    int*    flag_list  = (int*)(ws + OFF_FLAGL);
    int*    flag2_list = (int*)(ws + OFF_FLAG2L);
    float*  pb1        = (float*)(ws + OFF_PB1);
    float*  pb2        = (float*)(ws + OFF_PB2);
    int*    pi1        = (int*)(ws + OFF_PI1);
    u64*    eslot      = (u64*)(ws + OFF_ESLOT);
    double* n_sum      = (double*)(ws + OFF_SUMS);
    double* loss_part  = (double*)(ws + OFF_LOSSP);
    u16*    CBH        = (u16*)(ws + OFF_CBH);

    u16* XH  = (u16*)(out + XH_F);
    u16* PX2 = (u16*)(out + PX2_F);
    u16* CB2 = (u16*)(out + OUT_NCB);
    float* pb1h = out + PB1H_F;
    float* pb2h = out + PB2H_F;
    int*   pi1h = (int*)(out + PI1H_F);

    hipMemsetAsync(ws + OFF_CNTI, 0, (K + 2) * sizeof(u32), stream);
    hipMemsetAsync(ws + OFF_ESLOT, 0xFF, CAPE * sizeof(u64), stream);

    split_hi_kernel<<<N / 16, 256, 0, stream>>>(z_e, (u32x4*)XH);
    cbprep_kernel<<<K / 16, 256, 0, stream>>>(cbook, (u32x4*)CBH, (u32x4*)CB2, cnorm);

    argmin_hi_kernel<<<(N / BPH) * 4, 512, 0, stream>>>(CBH, XH, cnorm,
                                                        pb1h, pb2h, pi1h);

    merge_hi_kernel<<<N / 256, 256, 0, stream>>>(pb1h, pb2h, pi1h, idx_i,
                                                 out + OUT_IDX, flag_cnt, flag_list,
                                                 flag2_cnt, flag2_list);

    repack_kernel<<<CAP / 16, 256, 0, stream>>>(z_e, flag_cnt, flag_list, (u32x4*)PX2);

    argmin_part_kernel<<<(CAP / 128) * 16, 512, 0, stream>>>(CB2, PX2, cnorm, flag_cnt,
                                                             pb1, pb2, pi1);

    combine_kernel<<<CAP / 256, 256, 0, stream>>>(flag_cnt, flag_list, pb1, pb2, pi1,
                                                  idx_i, out + OUT_IDX,
                                                  flag2_cnt, flag2_list);

    exact_part_kernel<<<2048, 256, 0, stream>>>(z_e, cbook, cnorm, flag2_cnt,
                                                flag2_list, eslot);

    exact_write_kernel<<<CAPE / 256, 256, 0, stream>>>(flag2_cnt, flag2_list, eslot,
                                                       idx_i, out + OUT_IDX);

    count_kernel<<<N / 256, 256, 0, stream>>>(idx_i, cnti);

    scan_kernel<<<1, 256, 0, stream>>>(cnti, csz, offs, nxt, out + OUT_NCS, n_sum);

    fill_kernel<<<N / 256, 256, 0, stream>>>(idx_i, nxt, list);

    gather_finalize_kernel<<<K, 128, 0, stream>>>(z_e, cbook, offs, list, ema_w,
                                                  out + OUT_NCS, n_sum,
                                                  out + OUT_EMA, out + OUT_NCB,
                                                  out + OUT_ZQ, loss_part);

    loss_reduce_kernel<<<1, 256, 0, stream>>>(loss_part, out + OUT_LOSS);
}

// Round 18
// 740.172 us; speedup vs baseline: 1.2151x; 1.0067x over previous
//
#include <hip/hip_runtime.h>

// VQ-VAE EMA vector quantizer, MI355X.
// R18: tail consolidation on R17 (best: 745us, argmin_hi 437us).
// (1) counting distributed to final-idx sites (merge_hi/combine/exact_write),
//     count_kernel deleted; (2) eslot init at flag2-slot creation, 0xFF memset
//     deleted; (3) overflow guards keep the count partition exact.
// argmin_hi = R17 symmetric 256x256 tile (family minimum, R10-R17 mapped).

constexpr int N = 32768;   // B*L
constexpr int D = 512;
constexpr int K = 8192;
constexpr int CAP  = 8192;
constexpr int CAPE = 4096;

constexpr float DECAYF  = 0.99f;
constexpr float OMDECAY = (float)(1.0 - 0.99);
constexpr float EPSF    = 1e-6f;
constexpr float KEPSF   = (float)(8192 * 1e-6);
constexpr float TAU1    = 0.7f;
constexpr float TAU2    = 0.005f;

typedef unsigned int       u32;
typedef unsigned short     u16;
typedef unsigned long long u64;
typedef float  f32x4 __attribute__((ext_vector_type(4)));
typedef u32    u32x4 __attribute__((ext_vector_type(4)));
typedef __bf16 bf16x8 __attribute__((ext_vector_type(8)));

#define AS1 __attribute__((address_space(1)))
#define AS3 __attribute__((address_space(3)))

// ---- workspace layout (32-bit word offsets) ----
constexpr size_t OFF_CNORM  = 0;
constexpr size_t OFF_IDX    = OFF_CNORM + K;
constexpr size_t OFF_CNTI   = OFF_IDX + N;
constexpr size_t OFF_FLAGC  = OFF_CNTI + K;
constexpr size_t OFF_FLAG2C = OFF_FLAGC + 1;
constexpr size_t OFF_NEXT   = OFF_FLAG2C + 1;
constexpr size_t OFF_OFFS   = OFF_NEXT + K;
constexpr size_t OFF_LIST   = OFF_OFFS + K + 1;
constexpr size_t OFF_FLAGL  = OFF_LIST + N;
constexpr size_t OFF_FLAG2L = OFF_FLAGL + CAP;
constexpr size_t OFF_PB1    = OFF_FLAG2L + N;
constexpr size_t OFF_PB2    = OFF_PB1 + 16 * CAP;
constexpr size_t OFF_PI1    = OFF_PB2 + 16 * CAP;
constexpr size_t OFF_ESLOT  = (OFF_PI1 + 16 * CAP + 1) & ~(size_t)1;
constexpr size_t OFF_SUMS   = (OFF_ESLOT + 2 * CAPE + 1) & ~(size_t)1;
constexpr size_t OFF_LOSSP  = (OFF_SUMS + 2 + 1) & ~(size_t)1;
constexpr size_t OFF_CBH    = (OFF_LOSSP + 2 * K + 3) & ~(size_t)3;
static_assert((OFF_ESLOT & 1) == 0 && (OFF_SUMS & 1) == 0 && (OFF_LOSSP & 1) == 0, "align");
static_assert((OFF_CBH & 3) == 0, "16B align");

// ---- output layout (float offsets) ----
constexpr size_t OUT_ZQ   = 0;
constexpr size_t OUT_IDX  = OUT_ZQ + (size_t)N * D;
constexpr size_t OUT_LOSS = OUT_IDX + N;
constexpr size_t OUT_NCB  = OUT_LOSS + 1;
constexpr size_t OUT_NCS  = OUT_NCB + (size_t)K * D;
constexpr size_t OUT_EMA  = OUT_NCS + K;
constexpr size_t XH_F  = OUT_ZQ;
constexpr size_t PX2_F = OUT_ZQ + (size_t)N * 256;
constexpr size_t PB1H_F = OUT_EMA;
constexpr size_t PB2H_F = OUT_EMA + 4 * (size_t)N;
constexpr size_t PI1H_F = OUT_EMA + 8 * (size_t)N;

// ---------------------------------------------------------------------------
__device__ inline u16 f32_to_bf16_rne(float f)
{
    u32 u = __builtin_bit_cast(u32, f);
    u = (u + 0x7FFFu + ((u >> 16) & 1u)) >> 16;
    return (u16)u;
}

// hi-only split of z_e: [rows/16][16 slices][64 lanes][8 u16]
__global__ __launch_bounds__(256) void split_hi_kernel(const float* __restrict__ src,
                                                       u32x4* __restrict__ dst)
{
    const int T = blockIdx.x;
    const int w = threadIdx.x >> 6;
    const int l = threadIdx.x & 63;
    const int row = T * 16 + (l & 15);
#pragma unroll
    for (int i = 0; i < 4; ++i) {
        const int S  = w * 4 + i;
        const int q4 = S * 8 + (l >> 4) * 2;
        const float4 va = ((const float4*)src)[(size_t)row * 128 + q4];
        const float4 vb = ((const float4*)src)[(size_t)row * 128 + q4 + 1];
        const float a[8] = {va.x, va.y, va.z, va.w, vb.x, vb.y, vb.z, vb.w};
        u32x4 o;
#pragma unroll
        for (int j = 0; j < 4; ++j)
            ((u32*)&o)[j] = (u32)f32_to_bf16_rne(a[2 * j]) |
                            ((u32)f32_to_bf16_rne(a[2 * j + 1]) << 16);
        dst[((size_t)T * 16 + S) * 64 + l] = o;
    }
}

// fused codebook prep: hi-split -> CBH, interleaved split -> CB2, norms -> cnorm
__global__ __launch_bounds__(256) void cbprep_kernel(const float* __restrict__ cb,
                                                     u32x4* __restrict__ CBH,
                                                     u32x4* __restrict__ CB2,
                                                     float* __restrict__ cnorm)
{
    const int T = blockIdx.x;
    const int w = threadIdx.x >> 6;
    const int l = threadIdx.x & 63;
    {
        const int row = T * 16 + (l & 15);
#pragma unroll
        for (int i = 0; i < 4; ++i) {
            const int S  = w * 4 + i;
            const int q4 = S * 8 + (l >> 4) * 2;
            const float4 va = ((const float4*)cb)[(size_t)row * 128 + q4];
            const float4 vb = ((const float4*)cb)[(size_t)row * 128 + q4 + 1];
            const float a[8] = {va.x, va.y, va.z, va.w, vb.x, vb.y, vb.z, vb.w};
            u32x4 o;
#pragma unroll
            for (int j = 0; j < 4; ++j)
                ((u32*)&o)[j] = (u32)f32_to_bf16_rne(a[2 * j]) |
                                ((u32)f32_to_bf16_rne(a[2 * j + 1]) << 16);
            CBH[((size_t)T * 16 + S) * 64 + l] = o;
        }
    }
    {
        const int row = T * 16 + (l & 15);
        const int cq  = l >> 4;
#pragma unroll
        for (int i = 0; i < 8; ++i) {
            const int S = w + 4 * i;
            const float4 v = ((const float4*)cb)[(size_t)row * 128 + S * 4 + cq];
            u32x4 o;
            const float a[4] = {v.x, v.y, v.z, v.w};
#pragma unroll
            for (int j = 0; j < 4; ++j) {
                const u16 hi = f32_to_bf16_rne(a[j]);
                const float hif = __builtin_bit_cast(float, (u32)hi << 16);
                const u16 lo = f32_to_bf16_rne(a[j] - hif);
                ((u32*)&o)[j] = (u32)hi | ((u32)lo << 16);
            }
            CB2[((size_t)T * 32 + S) * 64 + l] = o;
        }
    }
#pragma unroll
    for (int sub = 0; sub < 4; ++sub) {
        const int row = T * 16 + sub * 4 + w;
        const float4* r = (const float4*)(cb + (size_t)row * D);
        const float4 v0 = r[l];
        const float4 v1 = r[l + 64];
        float s = v0.x * v0.x + v0.y * v0.y + v0.z * v0.z + v0.w * v0.w
                + v1.x * v1.x + v1.y * v1.y + v1.z * v1.z + v1.w * v1.w;
#pragma unroll
        for (int m = 32; m >= 1; m >>= 1) s += __shfl_xor(s, m, 64);
        if (l == 0) cnorm[row] = s;
    }
}

// indirect split of flagged points -> PX2 interleaved frag order
__global__ __launch_bounds__(256) void repack_kernel(
    const float* __restrict__ z_e, const int* __restrict__ flag_cnt,
    const int* __restrict__ flag_list, u32x4* __restrict__ PX2)
{
    const int B = blockIdx.x;
    const int cnt = min(*flag_cnt, CAP);
    if (B * 16 >= cnt) return;
    const int w = threadIdx.x >> 6;
    const int l = threadIdx.x & 63;
    const int srow = B * 16 + (l & 15);
    const int n = (srow < cnt) ? (flag_list[srow] & (N - 1)) : 0;
    const int cq = l >> 4;
#pragma unroll
    for (int i = 0; i < 8; ++i) {
        const int S = w + 4 * i;
        const float4 v = ((const float4*)z_e)[(size_t)n * 128 + S * 4 + cq];
        u32x4 o;
        const float a[4] = {v.x, v.y, v.z, v.w};
#pragma unroll
        for (int j = 0; j < 4; ++j) {
            const u16 hi = f32_to_bf16_rne(a[j]);
            const float hif = __builtin_bit_cast(float, (u32)hi << 16);
            const u16 lo = f32_to_bf16_rne(a[j] - hif);
            ((u32*)&o)[j] = (u32)hi | ((u32)lo << 16);
        }
        PX2[((size_t)B * 32 + S) * 64 + l] = o;
    }
}

// ---------------------------------------------------------------------------
// Pass 1: hi-only argmin, symmetric tile BP=256 x BC=256 (R17, family minimum).
constexpr int BPH = 256, BCH = 256, KIH = 32;
constexpr int NSTEPH = 16;
constexpr int NCHQ   = 8;
constexpr int TOTQ   = NCHQ * NSTEPH;      // 128 steps/block
constexpr int CELH = BCH * KIH;            // 8192 u16 (16KB)
constexpr int XELH = BPH * KIH;            // 8192 u16 (16KB)
constexpr int BUFH = CELH + XELH;          // 16384 u16 (32KB)

__global__ __launch_bounds__(512, 2) void argmin_hi_kernel(
    const u16* __restrict__ CBH, const u16* __restrict__ XH,
    const float* __restrict__ cnorm,
    float* __restrict__ pb1h, float* __restrict__ pb2h, int* __restrict__ pi1h)
{
    __shared__ __align__(16) u16 lds[2][BUFH];   // 64 KB

    const int b    = blockIdx.x;
    const int kq   = (b & 7) >> 1;
    const int n0   = ((b >> 3) * 2 + (b & 1)) * BPH;
    const int tid  = threadIdx.x;
    const int w    = tid >> 6;
    const int wp   = w >> 2;
    const int wc   = w & 3;
    const int lane = tid & 63;
    const int lhi  = lane >> 4;

    u32 cbo[2], xo[2];
#pragma unroll
    for (int m = 0; m < 2; ++m) {
        const int flat = m * 512 + tid;
        const int g = flat >> 6, li = flat & 63;
        cbo[m] = (u32)((kq * 128 + g) * 8192 + li * 8);
        xo[m]  = (u32)((n0 / 16 + g) * 8192 + li * 8);
    }

    auto stage = [&](int parity) {
        u16* bufp = &lds[parity][0];
#pragma unroll
        for (int m = 0; m < 2; ++m) {
            __builtin_amdgcn_global_load_lds((const AS1 u32*)(CBH + cbo[m]),
                (AS3 u32*)(bufp + (m * 512 + tid) * 8), 16, 0, 0);
            cbo[m] += 512;
            __builtin_amdgcn_global_load_lds((const AS1 u32*)(XH + xo[m]),
                (AS3 u32*)(bufp + CELH + (m * 512 + tid) * 8), 16, 0, 0);
            xo[m] += 512;
        }
    };

    float b1[8], b2[8]; int i1[8];
#pragma unroll
    for (int p = 0; p < 8; ++p) { b1[p] = INFINITY; b2[p] = INFINITY; i1[p] = 0; }

    stage(0);
    __syncthreads();
    int sc = 1;

    for (int cc = 0; cc < NCHQ; ++cc) {
        f32x4 acc[4][8];
        const f32x4 zero = {0.f, 0.f, 0.f, 0.f};
#pragma unroll
        for (int cg = 0; cg < 4; ++cg)
#pragma unroll
            for (int p = 0; p < 8; ++p) acc[cg][p] = zero;

        for (int s8 = 0; s8 < NSTEPH; ++s8) {
            const u16* cur = &lds[s8 & 1][0];
            if (sc < TOTQ) {
                if ((sc & (NSTEPH - 1)) == 0) {
#pragma unroll
                    for (int m = 0; m < 2; ++m) {
                        cbo[m] += 16 * 8192 - 8192;
                        xo[m]  -= 8192;
                    }
                }
                stage(sc & 1);
                ++sc;
            }
            u32x4 bfr[8];
#pragma unroll
            for (int p = 0; p < 8; ++p)
                bfr[p] = *(const u32x4*)(cur + CELH + (wp * 8 + p) * 512 + lane * 8);
#pragma unroll
            for (int cg = 0; cg < 4; ++cg) {
                const u32x4 af = *(const u32x4*)(cur + (wc * 4 + cg) * 512 + lane * 8);
#pragma unroll
                for (int p = 0; p < 8; ++p)
                    acc[cg][p] = __builtin_amdgcn_mfma_f32_16x16x32_bf16(
                        __builtin_bit_cast(bf16x8, af),
                        __builtin_bit_cast(bf16x8, bfr[p]), acc[cg][p], 0, 0, 0);
            }
            __syncthreads();
        }

        const int cb0 = kq * 2048 + cc * 256 + wc * 64;
#pragma unroll
        for (int cg = 0; cg < 4; ++cg) {
            const int code0 = cb0 + cg * 16 + lhi * 4;
            const float4 cn4 = *(const float4*)(cnorm + code0);
            const float cn[4] = {cn4.x, cn4.y, cn4.z, cn4.w};
#pragma unroll
            for (int p = 0; p < 8; ++p) {
                const f32x4 A = acc[cg][p];
                const float dv[4] = {cn[0] - 2.f * A.x, cn[1] - 2.f * A.y,
                                     cn[2] - 2.f * A.z, cn[3] - 2.f * A.w};
#pragma unroll
                for (int r = 0; r < 4; ++r) {
                    if (dv[r] < b1[p]) { b2[p] = b1[p]; b1[p] = dv[r]; i1[p] = code0 + r; }
                    else if (dv[r] < b2[p]) { b2[p] = dv[r]; }
                }
            }
        }
    }

#pragma unroll
    for (int p = 0; p < 8; ++p) {
#pragma unroll
        for (int m = 16; m <= 32; m <<= 1) {
            const float ob1 = __shfl_xor(b1[p], m, 64);
            const float ob2 = __shfl_xor(b2[p], m, 64);
            const int   oi1 = __shfl_xor(i1[p], m, 64);
            const float nb2 = fminf(fminf(b2[p], ob2), fmaxf(b1[p], ob1));
            if (ob1 < b1[p] || (ob1 == b1[p] && oi1 < i1[p])) { b1[p] = ob1; i1[p] = oi1; }
            b2[p] = nb2;
        }
    }

    __syncthreads();

    float* mb1 = (float*)&lds[0][0];
    float* mb2 = mb1 + 8 * 128;
    int*   mi  = (int*)(mb2 + 8 * 128);
    if (lane < 16) {
#pragma unroll
        for (int p = 0; p < 8; ++p) {
            const int pt = p * 16 + lane;
            mb1[w * 128 + pt] = b1[p];
            mb2[w * 128 + pt] = b2[p];
            mi [w * 128 + pt] = i1[p];
        }
    }
    __syncthreads();
    if (tid < BPH) {
        const int wp2 = tid >> 7;
        const int pt  = tid & 127;
        float fb1 = INFINITY, fb2 = INFINITY; int fi = 0;
        for (int ww = 0; ww < 4; ++ww) {
            const int src = (wp2 * 4 + ww) * 128 + pt;
            const float a1 = mb1[src], a2 = mb2[src];
            const int   ai = mi[src];
            const float nb2 = fminf(fminf(fb2, a2), fmaxf(fb1, a1));
            if (a1 < fb1 || (a1 == fb1 && ai < fi)) { fb1 = a1; fi = ai; }
            fb2 = nb2;
        }
        const int n = n0 + tid;
        pb1h[kq * N + n] = fb1;
        pb2h[kq * N + n] = fb2;
        pi1h[kq * N + n] = fi;
    }
}

// ---------------------------------------------------------------------------
// merge 4 K-quarter partials; count unflagged points (final idx here).
__global__ __launch_bounds__(256) void merge_hi_kernel(
    const float* __restrict__ pb1h, const float* __restrict__ pb2h,
    const int* __restrict__ pi1h,
    int* __restrict__ idx_i, float* __restrict__ idx_f,
    int* __restrict__ flag_cnt, int* __restrict__ flag_list,
    int* __restrict__ flag2_cnt, int* __restrict__ flag2_list,
    int* __restrict__ cnti, u64* __restrict__ eslot)
{
    const int n = blockIdx.x * 256 + threadIdx.x;
    float fb1 = INFINITY, fb2 = INFINITY; int fi = 0x7fffffff;
#pragma unroll
    for (int q = 0; q < 4; ++q) {
        const float a1 = pb1h[q * N + n], a2 = pb2h[q * N + n];
        const int   ai = pi1h[q * N + n];
        const float nb2 = fminf(fminf(fb2, a2), fmaxf(fb1, a1));
        if (a1 < fb1 || (a1 == fb1 && ai < fi)) { fb1 = a1; fi = ai; }
        fb2 = nb2;
    }
    idx_i[n] = fi;
    idx_f[n] = (float)fi;
    if (fb2 - fb1 < TAU1) {
        const int pos = atomicAdd(flag_cnt, 1);
        if (pos < CAP) flag_list[pos] = n;
        else {
            const int p2 = atomicAdd(flag2_cnt, 1);
            if (p2 < CAPE) { flag2_list[p2] = n; eslot[p2] = ~0ull; }
            else atomicAdd(&cnti[fi & (K - 1)], 1);   // overflow: idx final here
        }
    } else {
        atomicAdd(&cnti[fi & (K - 1)], 1);            // final idx: count now
    }
}

// ---------------------------------------------------------------------------
// Pass 2: split-precision argmin, ONE 512-code chunk per block (R17).
constexpr int CEL2 = 512 * 32;
constexpr int XEL2 = 128 * 32;
constexpr int BUF2 = CEL2 + XEL2;

__global__ __launch_bounds__(512, 2) void argmin_part_kernel(
    const u16* __restrict__ CB2, const u16* __restrict__ PX2,
    const float* __restrict__ cnorm, const int* __restrict__ flag_cnt,
    float* __restrict__ pb1, float* __restrict__ pb2, int* __restrict__ pi1)
{
    const int q  = blockIdx.x & 15;
    const int sb = blockIdx.x >> 4;
    const int cnt = min(*flag_cnt, CAP);
    if (sb * 128 >= cnt) return;
    const int n0s = sb * 128;

    __shared__ __align__(16) u16 lds[2][BUF2];

    const int tid  = threadIdx.x;
    const int w    = tid >> 6;
    const int lane = tid & 63;
    const int lhi  = lane >> 4;

    auto stage = [&](u16* bufp, int s) {
#pragma unroll
        for (int j = 0; j < 4; ++j) {
            const int slot = j * 512 + tid;
            const u16* gsrc = CB2 + (((size_t)(q * 32 + (slot >> 6)) * 32 + s) * 512
                                     + (slot & 63) * 8);
            __builtin_amdgcn_global_load_lds((const AS1 u32*)gsrc,
                                             (AS3 u32*)(bufp + slot * 8), 16, 0, 0);
        }
        const u16* gx = PX2 + (((size_t)(n0s / 16 + (tid >> 6)) * 32 + s) * 512
                               + (tid & 63) * 8);
        __builtin_amdgcn_global_load_lds((const AS1 u32*)gx,
                                         (AS3 u32*)(bufp + CEL2 + tid * 8), 16, 0, 0);
    };

    float b1[8], b2[8]; int i1[8];
#pragma unroll
    for (int p = 0; p < 8; ++p) { b1[p] = INFINITY; b2[p] = INFINITY; i1[p] = 0; }

    f32x4 acc[4][8];
    const f32x4 zero = {0.f, 0.f, 0.f, 0.f};
#pragma unroll
    for (int cg = 0; cg < 4; ++cg)
#pragma unroll
        for (int p = 0; p < 8; ++p) acc[cg][p] = zero;

    stage(&lds[0][0], 0);
    __syncthreads();

#pragma unroll 2
    for (int s = 0; s < 32; ++s) {
        const u16* cur = (s & 1) ? &lds[1][0] : &lds[0][0];
        u16* nxt       = (s & 1) ? &lds[0][0] : &lds[1][0];
        if (s + 1 < 32) stage(nxt, s + 1);

        u32x4 bfr[8];
#pragma unroll
        for (int p = 0; p < 8; ++p)
            bfr[p] = *(const u32x4*)(cur + CEL2 + p * 512 + lane * 8);
#pragma unroll
        for (int cg = 0; cg < 4; ++cg) {
            const u32x4 af = *(const u32x4*)(cur + (w * 4 + cg) * 512 + lane * 8);
            u32x4 as;
            as.x = (af.x >> 16) | (af.x << 16);
            as.y = (af.y >> 16) | (af.y << 16);
            as.z = (af.z >> 16) | (af.z << 16);
            as.w = (af.w >> 16) | (af.w << 16);
#pragma unroll
            for (int p = 0; p < 8; ++p) {
                acc[cg][p] = __builtin_amdgcn_mfma_f32_16x16x32_bf16(
                    __builtin_bit_cast(bf16x8, af), __builtin_bit_cast(bf16x8, bfr[p]),
                    acc[cg][p], 0, 0, 0);
                acc[cg][p] = __builtin_amdgcn_mfma_f32_16x16x32_bf16(
                    __builtin_bit_cast(bf16x8, as), __builtin_bit_cast(bf16x8, bfr[p]),
                    acc[cg][p], 0, 0, 0);
            }
        }
        __syncthreads();
    }

    const int cb0 = q * 512 + w * 64;
#pragma unroll
    for (int cg = 0; cg < 4; ++cg) {
        const int code0 = cb0 + cg * 16 + lhi * 4;
        const float4 cn4 = *(const float4*)(cnorm + code0);
        const float cn[4] = {cn4.x, cn4.y, cn4.z, cn4.w};
#pragma unroll
        for (int p = 0; p < 8; ++p) {
            const f32x4 A = acc[cg][p];
            const float dv[4] = {cn[0] - 2.f * A.x, cn[1] - 2.f * A.y,
                                 cn[2] - 2.f * A.z, cn[3] - 2.f * A.w};
#pragma unroll
            for (int r = 0; r < 4; ++r) {
                if (dv[r] < b1[p]) { b2[p] = b1[p]; b1[p] = dv[r]; i1[p] = code0 + r; }
                else if (dv[r] < b2[p]) { b2[p] = dv[r]; }
            }
        }
    }

#pragma unroll
    for (int p = 0; p < 8; ++p) {
#pragma unroll
        for (int m = 16; m <= 32; m <<= 1) {
            const float ob1 = __shfl_xor(b1[p], m, 64);
            const float ob2 = __shfl_xor(b2[p], m, 64);
            const int   oi1 = __shfl_xor(i1[p], m, 64);
            const float nb2 = fminf(fminf(b2[p], ob2), fmaxf(b1[p], ob1));
            if (ob1 < b1[p] || (ob1 == b1[p] && oi1 < i1[p])) { b1[p] = ob1; i1[p] = oi1; }
            b2[p] = nb2;
        }
    }

    __syncthreads();

    float* mb1 = (float*)&lds[0][0];
    float* mb2 = mb1 + 8 * 128;
    int*   mi  = (int*)(mb2 + 8 * 128);
    if (lane < 16) {
#pragma unroll
        for (int p = 0; p < 8; ++p) {
            const int pt = p * 16 + lane;
            mb1[w * 128 + pt] = b1[p];
            mb2[w * 128 + pt] = b2[p];
            mi [w * 128 + pt] = i1[p];
        }
    }
    __syncthreads();
    if (tid < 128) {
        float fb1 = INFINITY, fb2 = INFINITY; int fi = 0;
        for (int ww = 0; ww < 8; ++ww) {
            const float a1 = mb1[ww * 128 + tid], a2 = mb2[ww * 128 + tid];
            const int   ai = mi[ww * 128 + tid];
            const float nb2 = fminf(fminf(fb2, a2), fmaxf(fb1, a1));
            if (a1 < fb1 || (a1 == fb1 && ai < fi)) { fb1 = a1; fi = ai; }
            fb2 = nb2;
        }
        const int slot = n0s + tid;
        pb1[q * CAP + slot] = fb1;
        pb2[q * CAP + slot] = fb2;
        pi1[q * CAP + slot] = fi;
    }
}

// ---------------------------------------------------------------------------
// merge 16 code-chunk partials; count pass-2-final points; init flag2 eslots.
__global__ __launch_bounds__(256) void combine_kernel(
    const int* __restrict__ flag_cnt, const int* __restrict__ flag_list,
    const float* __restrict__ pb1, const float* __restrict__ pb2,
    const int* __restrict__ pi1,
    int* __restrict__ idx_i, float* __restrict__ idx_f,
    int* __restrict__ flag2_cnt, int* __restrict__ flag2_list,
    int* __restrict__ cnti, u64* __restrict__ eslot)
{
    const int s = blockIdx.x * 256 + threadIdx.x;
    const int cnt = min(*flag_cnt, CAP);
    if (s >= cnt) return;
    float fb1 = INFINITY, fb2 = INFINITY; int fi = 0x7fffffff;
#pragma unroll
    for (int q = 0; q < 16; ++q) {
        const float a1 = pb1[q * CAP + s], a2 = pb2[q * CAP + s];
        const int   ai = pi1[q * CAP + s];
        const float nb2 = fminf(fminf(fb2, a2), fmaxf(fb1, a1));
        if (a1 < fb1 || (a1 == fb1 && ai < fi)) { fb1 = a1; fi = ai; }
        fb2 = nb2;
    }
    const int n = flag_list[s] & (N - 1);
    idx_i[n] = fi;
    idx_f[n] = (float)fi;
    if (fb2 - fb1 < TAU2) {
        const int p2 = atomicAdd(flag2_cnt, 1);
        if (p2 < CAPE) { flag2_list[p2] = n; eslot[p2] = ~0ull; }
        else atomicAdd(&cnti[fi & (K - 1)], 1);       // overflow: idx final here
    } else {
        atomicAdd(&cnti[fi & (K - 1)], 1);            // final idx: count now
    }
}

// ---------------------------------------------------------------------------
__global__ __launch_bounds__(256) void exact_part_kernel(
    const float* __restrict__ x, const float* __restrict__ cb,
    const float* __restrict__ cnorm, const int* __restrict__ flag2_cnt,
    const int* __restrict__ flag2_list, u64* __restrict__ eslot)
{
    __shared__ float4 xs[128];
    __shared__ u64 red[256];
    const int cnt = min(*flag2_cnt, CAPE);
    const int nwork = cnt * 16;
    for (int j = blockIdx.x; j < nwork; j += gridDim.x) {
        const int s = j >> 4;
        const int q = j & 15;
        const int n = flag2_list[s] & (N - 1);
        __syncthreads();
        if (threadIdx.x < 128)
            xs[threadIdx.x] = ((const float4*)(x + (size_t)n * D))[threadIdx.x];
        __syncthreads();
        u64 bestp = ~0ull;
#pragma unroll
        for (int c = 0; c < 2; ++c) {
            const int k = q * 512 + c * 256 + threadIdx.x;
            const float4* crow = (const float4*)(cb + (size_t)k * D);
            float a0 = 0.f, a1 = 0.f, a2 = 0.f, a3 = 0.f;
            for (int d = 0; d < 128; ++d) {
                const float4 xv = xs[d], cv = crow[d];
                a0 = fmaf(xv.x, cv.x, a0);
                a1 = fmaf(xv.y, cv.y, a1);
                a2 = fmaf(xv.z, cv.z, a2);
                a3 = fmaf(xv.w, cv.w, a3);
            }
            const float dist = cnorm[k] - 2.0f * ((a0 + a1) + (a2 + a3));
            u32 ub = __builtin_bit_cast(u32, dist);
            ub = (ub & 0x80000000u) ? ~ub : (ub | 0x80000000u);
            const u64 pk = ((u64)ub << 32) | (u32)k;
            bestp = bestp < pk ? bestp : pk;
        }
        red[threadIdx.x] = bestp;
        __syncthreads();
        for (int off = 128; off > 0; off >>= 1) {
            if (threadIdx.x < off) {
                const u64 o = red[threadIdx.x + off];
                if (o < red[threadIdx.x]) red[threadIdx.x] = o;
            }
            __syncthreads();
        }
        if (threadIdx.x == 0) atomicMin(&eslot[s], red[0]);
    }
}

// write exact results + count them (final idx site for flag2 points)
__global__ __launch_bounds__(256) void exact_write_kernel(
    const int* __restrict__ flag2_cnt, const int* __restrict__ flag2_list,
    const u64* __restrict__ eslot, int* __restrict__ idx_i, float* __restrict__ idx_f,
    int* __restrict__ cnti)
{
    const int s = blockIdx.x * 256 + threadIdx.x;
    const int cnt = min(*flag2_cnt, CAPE);
    if (s >= cnt) return;
    const int n = flag2_list[s] & (N - 1);
    const int k = (int)(eslot[s] & (u64)(K - 1));
    idx_i[n] = k;
    idx_f[n] = (float)k;
    atomicAdd(&cnti[k], 1);
}

// ---------------------------------------------------------------------------
__global__ __launch_bounds__(256) void scan_kernel(
    const int* __restrict__ cnti, const float* __restrict__ csz,
    int* __restrict__ offs, int* __restrict__ nxt,
    float* __restrict__ ncs, double* __restrict__ n_sum)
{
    __shared__ int    tsum[256];
    __shared__ double dsum[256];
    const int t = threadIdx.x;
    const int base = t * 32;
    int s = 0;
    double dn = 0.0;
#pragma unroll
    for (int i = 0; i < 32; ++i) {
        const int c = cnti[base + i];
        s += c;
        const float v = DECAYF * csz[base + i] + OMDECAY * (float)c;
        ncs[base + i] = v;
        dn += (double)v;
    }
    tsum[t] = s; dsum[t] = dn;
    __syncthreads();
    int run = 0;
    for (int j = 0; j < t; ++j) run += tsum[j];
#pragma unroll
    for (int i = 0; i < 32; ++i) {
        offs[base + i] = run;
        nxt[base + i] = run;
        run += cnti[base + i];
    }
    if (t == 255) offs[K] = run;
    if (t == 0) {
        double tot = 0.0;
        for (int j = 0; j < 256; ++j) tot += dsum[j];
        n_sum[0] = tot;
    }
}

// ---------------------------------------------------------------------------
__global__ __launch_bounds__(256) void fill_kernel(
    const int* __restrict__ idx_i, int* __restrict__ nxt, int* __restrict__ list)
{
    const int p = blockIdx.x * 256 + threadIdx.x;
    const int k = idx_i[p] & (K - 1);
    const int pos = atomicAdd(&nxt[k], 1);
    if ((unsigned)pos < (unsigned)N) list[pos] = p;
}

// ---------------------------------------------------------------------------
__global__ __launch_bounds__(128) void gather_finalize_kernel(
    const float* __restrict__ x, const float* __restrict__ cb,
    const int* __restrict__ offs, const int* __restrict__ list,
    const float* __restrict__ ema_w, const float* __restrict__ ncs,
    const double* __restrict__ n_sum, float* __restrict__ new_ema,
    float* __restrict__ new_cb, float* __restrict__ zq,
    double* __restrict__ loss_part)
{
    const int k = blockIdx.x;
    const int t = threadIdx.x;
    const int beg = min(offs[k], N), end = min(offs[k + 1], N);
    const size_t o = (size_t)k * 128 + t;
    const float4 c = ((const float4*)cb)[o];
    float4 acc = {0.f, 0.f, 0.f, 0.f};
    float lsum = 0.f;
    for (int i = beg; i < end; ++i) {
        const int p = list[i] & (N - 1);
        const float4 v = ((const float4*)x)[(size_t)p * 128 + t];
        acc.x += v.x; acc.y += v.y; acc.z += v.z; acc.w += v.w;
        ((float4*)zq)[(size_t)p * 128 + t] = c;
        const float d0 = v.x - c.x, d1 = v.y - c.y, d2 = v.z - c.z, d3 = v.w - c.w;
        lsum += d0 * d0 + d1 * d1 + d2 * d2 + d3 * d3;
    }
    const float n = (float)n_sum[0];
    const float csm = (ncs[k] + EPSF) / (n + KEPSF) * n;
    const float4 e = ((const float4*)ema_w)[o];
    float4 ne;
    ne.x = DECAYF * e.x + OMDECAY * acc.x;
    ne.y = DECAYF * e.y + OMDECAY * acc.y;
    ne.z = DECAYF * e.z + OMDECAY * acc.z;
    ne.w = DECAYF * e.w + OMDECAY * acc.w;
    ((float4*)new_ema)[o] = ne;
    float4 nc;
    nc.x = ne.x / csm; nc.y = ne.y / csm; nc.z = ne.z / csm; nc.w = ne.w / csm;
    ((float4*)new_cb)[o] = nc;

#pragma unroll
    for (int m = 32; m >= 1; m >>= 1) lsum += __shfl_xor(lsum, m, 64);
    __shared__ float prt[2];
    if ((t & 63) == 0) prt[t >> 6] = lsum;
    __syncthreads();
    if (t == 0) loss_part[k] = (double)(prt[0] + prt[1]);
}

// ---------------------------------------------------------------------------
__global__ __launch_bounds__(256) void loss_reduce_kernel(
    const double* __restrict__ loss_part, float* __restrict__ out_loss)
{
    __shared__ double red[256];
    const int t = threadIdx.x;
    double s = 0.0;
    for (int i = t; i < K; i += 256) s += loss_part[i];
    red[t] = s;
    __syncthreads();
    for (int off = 128; off > 0; off >>= 1) {
        if (t < off) red[t] += red[t + off];
        __syncthreads();
    }
    if (t == 0)
        out_loss[0] = (float)(1.25 * (red[0] / (double)((size_t)N * D)));
}

// ---------------------------------------------------------------------------
extern "C" void kernel_launch(void* const* d_in, const int* in_sizes, int n_in,
                              void* d_out, int out_size, void* d_ws, size_t ws_size,
                              hipStream_t stream)
{
    const float* z_e   = (const float*)d_in[0];
    const float* cbook = (const float*)d_in[1];
    const float* csz   = (const float*)d_in[2];
    const float* ema_w = (const float*)d_in[3];

    float* out = (float*)d_out;
    u32*   ws  = (u32*)d_ws;

    float*  cnorm      = (float*)(ws + OFF_CNORM);
    int*    idx_i      = (int*)(ws + OFF_IDX);
    int*    cnti       = (int*)(ws + OFF_CNTI);
    int*    flag_cnt   = (int*)(ws + OFF_FLAGC);
    int*    flag2_cnt  = (int*)(ws + OFF_FLAG2C);
    int*    nxt        = (int*)(ws + OFF_NEXT);
    int*    offs       = (int*)(ws + OFF_OFFS);
    int*    list       = (int*)(ws + OFF_LIST);
    int*    flag_list  = (int*)(ws + OFF_FLAGL);
    int*    flag2_list = (int*)(ws + OFF_FLAG2L);
    float*  pb1        = (float*)(ws + OFF_PB1);
    float*  pb2        = (float*)(ws + OFF_PB2);
    int*    pi1        = (int*)(ws + OFF_PI1);
    u64*    eslot      = (u64*)(ws + OFF_ESLOT);
    double* n_sum      = (double*)(ws + OFF_SUMS);
    double* loss_part  = (double*)(ws + OFF_LOSSP);
    u16*    CBH        = (u16*)(ws + OFF_CBH);

    u16* XH  = (u16*)(out + XH_F);
    u16* PX2 = (u16*)(out + PX2_F);
    u16* CB2 = (u16*)(out + OUT_NCB);
    float* pb1h = out + PB1H_F;
    float* pb2h = out + PB2H_F;
    int*   pi1h = (int*)(out + PI1H_F);

    hipMemsetAsync(ws + OFF_CNTI, 0, (K + 2) * sizeof(u32), stream);

    split_hi_kernel<<<N / 16, 256, 0, stream>>>(z_e, (u32x4*)XH);
    cbprep_kernel<<<K / 16, 256, 0, stream>>>(cbook, (u32x4*)CBH, (u32x4*)CB2, cnorm);

    argmin_hi_kernel<<<(N / BPH) * 4, 512, 0, stream>>>(CBH, XH, cnorm,
                                                        pb1h, pb2h, pi1h);

    merge_hi_kernel<<<N / 256, 256, 0, stream>>>(pb1h, pb2h, pi1h, idx_i,
                                                 out + OUT_IDX, flag_cnt, flag_list,
                                                 flag2_cnt, flag2_list, cnti, eslot);

    repack_kernel<<<CAP / 16, 256, 0, stream>>>(z_e, flag_cnt, flag_list, (u32x4*)PX2);

    argmin_part_kernel<<<(CAP / 128) * 16, 512, 0, stream>>>(CB2, PX2, cnorm, flag_cnt,
                                                             pb1, pb2, pi1);

    combine_kernel<<<CAP / 256, 256, 0, stream>>>(flag_cnt, flag_list, pb1, pb2, pi1,
                                                  idx_i, out + OUT_IDX,
                                                  flag2_cnt, flag2_list, cnti, eslot);

    exact_part_kernel<<<2048, 256, 0, stream>>>(z_e, cbook, cnorm, flag2_cnt,
                                                flag2_list, eslot);

    exact_write_kernel<<<CAPE / 256, 256, 0, stream>>>(flag2_cnt, flag2_list, eslot,
                                                       idx_i, out + OUT_IDX, cnti);

    scan_kernel<<<1, 256, 0, stream>>>(cnti, csz, offs, nxt, out + OUT_NCS, n_sum);

    fill_kernel<<<N / 256, 256, 0, stream>>>(idx_i, nxt, list);

    gather_finalize_kernel<<<K, 128, 0, stream>>>(z_e, cbook, offs, list, ema_w,
                                                  out + OUT_NCS, n_sum,
                                                  out + OUT_EMA, out + OUT_NCB,
                                                  out + OUT_ZQ, loss_part);

    loss_reduce_kernel<<<1, 256, 0, stream>>>(loss_part, out + OUT_LOSS);
}